// Round 4
// baseline (612.472 us; speedup 1.0000x reference)
//
#include <hip/hip_runtime.h>
#include <hip/hip_bf16.h>

#define N_NODES 100000
#define N_EDGES 800000
#define BGRAPH  4000
#define GNN_IN  428
#define HDIM    64
#define HID     512
#define EMBD    300
#define AIN     1112   // 512 + 600
#define CAP     48     // max in-degree capacity (Poisson(8); actual max ~30)
#define LSTR    72     // LDS row stride (ushorts): 2-way bank alias only (free, m136)
#define XSTR    456    // k_gemm_xw LDS row stride (u16): word-stride 228 % 32 == 4 -> 2-way alias (free)

typedef unsigned short u16;
typedef short bf16x8 __attribute__((ext_vector_type(8)));   // MFMA A/B frag (8 bf16, 4 VGPRs)
typedef float f32x4  __attribute__((ext_vector_type(4)));   // MFMA C/D frag

__device__ __forceinline__ u16 f2bf(float f) {
    union { float f; unsigned int u; } v; v.f = f;
    unsigned int r = v.u + 0x7FFFu + ((v.u >> 16) & 1u);    // RNE
    return (u16)(r >> 16);
}
__device__ __forceinline__ float bf2f(u16 u) {
    union { unsigned int u; float f; } v; v.u = ((unsigned int)u) << 16;
    return v.f;
}

// ---------------- merged prep: w0T, fwT, five 64x64 transposes, A[:,512:] ----------------
#define R_W0T   (64 * 448)          // 28672
#define R_FWT   (512 * 1120)        // 573440
#define R_W64   (5 * 4096)          // 20480
#define R_ORIG  (BGRAPH * 600)      // 2400000
#define PREP_TOT (R_W0T + R_FWT + R_W64 + R_ORIG)

__global__ void k_prep_all(const float* __restrict__ w1_0, const float* __restrict__ final_w,
                           const float* __restrict__ w2_0, const float* __restrict__ w1_1,
                           const float* __restrict__ w2_1, const float* __restrict__ w1_2,
                           const float* __restrict__ w2_2,
                           const int* __restrict__ pp, const float* __restrict__ ee,
                           u16* __restrict__ w0T, u16* __restrict__ fwT,
                           u16* __restrict__ wT5, u16* __restrict__ A) {
    int idx = blockIdx.x * 256 + threadIdx.x;
    if (idx < R_W0T) {  // w0T[n][k] = bf16(w1_0[k][n]), zero-pad k to 448
        const int n = idx / 448, k = idx - n * 448;
        w0T[idx] = (k < GNN_IN) ? f2bf(w1_0[k * 64 + n]) : (u16)0;
        return;
    }
    idx -= R_W0T;
    if (idx < R_FWT) {  // fwT[n][k] = bf16(final_w[k][n]), zero-pad k to 1120
        const int n = idx / 1120, k = idx - n * 1120;
        fwT[idx] = (k < AIN) ? f2bf(final_w[(size_t)k * 512 + n]) : (u16)0;
        return;
    }
    idx -= R_FWT;
    if (idx < R_W64) {  // five 64x64 transposes: order w2_0, w1_1, w2_1, w1_2, w2_2
        const int which = idx >> 12;
        const int r = idx & 4095;
        const float* w = (which == 0) ? w2_0 : (which == 1) ? w1_1
                       : (which == 2) ? w2_1 : (which == 3) ? w1_2 : w2_2;
        wT5[(which << 12) + ((r & 63) << 6) + (r >> 6)] = f2bf(w[r]);
        return;
    }
    idx -= R_W64;
    if (idx < R_ORIG) { // A[:, 512:1112] = bf16(entity_embed[pred_pairs])
        const int b = idx / 600;
        const int j = idx - b * 600;
        const int which = (j >= 300) ? 1 : 0;
        const int cls = pp[b * 2 + which];
        A[(size_t)b * AIN + 512 + j] = f2bf(ee[cls * 300 + (j - which * 300)]);
    }
}

// ---------------- merged CSR fill + segment counts ----------------
__global__ void k_graph(const int* __restrict__ ei, int* __restrict__ deg,
                        int* __restrict__ csr2,
                        const int* __restrict__ bids, float* __restrict__ counts) {
    const int e = blockIdx.x * blockDim.x + threadIdx.x;
    if (e < N_EDGES) {
        const int s = ei[e];
        const int d = ei[N_EDGES + e];
        const int slot = atomicAdd(&deg[d], 1);
        if (slot < CAP) csr2[d * CAP + slot] = s;
    }
    if (e < N_NODES) {
        atomicAdd(&counts[bids[e]], 1.0f);
    }
}

// ---------------- y = bf16(x @ w1_0) — MFMA with coalesced LDS staging ----------------
// A block's 64 rows are a CONTIGUOUS 107-KB region of x: stream it with perfectly
// coalesced float4 loads (lane i -> consecutive addresses), convert to bf16 in LDS,
// then feed MFMA A-fragments from LDS. Fixes the 16-row scatter (~1 TB/s cap).
__global__ __launch_bounds__(256) void k_gemm_xw(const float* __restrict__ x,
                                                 const u16* __restrict__ w0T,
                                                 u16* __restrict__ y) {
    __shared__ u16 xs[64 * XSTR];
    const int t = threadIdx.x;
    const int lane = t & 63, wave = t >> 6;
    const int q = lane >> 4, m = lane & 15;
    const int n0 = blockIdx.x * 64;

    // zero pad cols 428..447 (read by the tt=13 fragment)
    for (int i = t; i < 64 * 20; i += 256) {
        const int r = i / 20, c = 428 + (i - r * 20);
        xs[r * XSTR + c] = 0;
    }
    // stage 64 rows x 428 cols (6848 float4s, contiguous in x), convert to bf16
#pragma unroll
    for (int i = 0; i < 27; ++i) {
        const int idx4 = t + i * 256;
        if (idx4 < 6848) {
            const int r = idx4 / 107, c4 = idx4 - r * 107;   // 428/4 = 107 float4 per row
            const int gr = min(n0 + r, N_NODES - 1);
            const float4 v = *reinterpret_cast<const float4*>(&x[(size_t)gr * GNN_IN + c4 * 4]);
            ushort4 o;
            o.x = f2bf(v.x); o.y = f2bf(v.y); o.z = f2bf(v.z); o.w = f2bf(v.w);
            *reinterpret_cast<ushort4*>(&xs[r * XSTR + c4 * 4]) = o;
        }
    }
    __syncthreads();

    f32x4 acc[4];
#pragma unroll
    for (int c = 0; c < 4; ++c) acc[c] = (f32x4){0.f, 0.f, 0.f, 0.f};

#pragma unroll
    for (int tt = 0; tt < 14; ++tt) {
        const int ka = tt * 32 + q * 8;
        const bf16x8 a = *reinterpret_cast<const bf16x8*>(&xs[(wave * 16 + m) * XSTR + ka]);
#pragma unroll
        for (int c = 0; c < 4; ++c) {
            const bf16x8 b = *reinterpret_cast<const bf16x8*>(&w0T[(c * 16 + m) * 448 + ka]);
            acc[c] = __builtin_amdgcn_mfma_f32_16x16x32_bf16(a, b, acc[c], 0, 0, 0);
        }
    }

    // C-layout: col = c*16 + m, row-in-tile = q*4 + r
#pragma unroll
    for (int c = 0; c < 4; ++c)
#pragma unroll
        for (int r = 0; r < 4; ++r) {
            const int rr = n0 + wave * 16 + q * 4 + r;
            if (rr < N_NODES) y[(size_t)rr * 64 + c * 16 + m] = f2bf(acc[c][r]);
        }
}

// fixed-16 predicated gather (deg>16 tail is the <1% Poisson tail), fp32 accumulate
__device__ __forceinline__ float gather16p(const u16* __restrict__ hin,
                                           const int* __restrict__ lst,
                                           int dg, int lane, float u) {
    const int4* l4 = reinterpret_cast<const int4*>(lst);
    const int4 ia = l4[0], ib = l4[1], ic = l4[2], id4 = l4[3];
    int id[16] = {ia.x, ia.y, ia.z, ia.w, ib.x, ib.y, ib.z, ib.w,
                  ic.x, ic.y, ic.z, ic.w, id4.x, id4.y, id4.z, id4.w};
    float v[16];
#pragma unroll
    for (int i = 0; i < 16; ++i) {
        const bool ok = (i < dg);
        const int idx = ok ? id[i] : 0;
        v[i] = bf2f(hin[(size_t)idx * 64 + lane]) * (ok ? 1.f : 0.f);
    }
#pragma unroll
    for (int i = 0; i < 16; ++i) u += v[i];
    if (__builtin_expect(dg > 16, 0)) {
        for (int e = 16; e < dg; e += 8) {
            const int4 a = l4[e >> 2];
            const int4 b = l4[(e >> 2) + 1];
            int id2[8] = {a.x, a.y, a.z, a.w, b.x, b.y, b.z, b.w};
#pragma unroll
            for (int i = 0; i < 8; ++i) {
                const bool ok = (e + i < dg);
                const int idx = ok ? id2[i] : 0;
                u += bf2f(hin[(size_t)idx * 64 + lane]) * (ok ? 1.f : 0.f);
            }
        }
    }
    return u;
}

// ---------------- layer 0 (w1 pre-applied): h = relu(relu(u+b1) @ w2 + b2) ----------
// Barrier-free: LDS rows are wave-private.
__global__ __launch_bounds__(256, 4) void k_gin0(const u16* __restrict__ y,
                                                 const int* __restrict__ deg,
                                                 const int* __restrict__ csr2,
                                                 const float* __restrict__ b1,
                                                 const u16* __restrict__ w2T,
                                                 const float* __restrict__ b2,
                                                 u16* __restrict__ hout) {
    __shared__ u16 zs[64 * LSTR];
    const int t = threadIdx.x;
    const int lane = t & 63, wave = t >> 6;
    const int q = lane >> 4, m = lane & 15;
    const int n0 = blockIdx.x * 64;
    const int base = n0 + wave * 16;
    const float b1v = b1[lane];
#pragma unroll 2
    for (int j = 0; j < 16; ++j) {
        const int n = min(base + j, N_NODES - 1);
        const int dg = min(deg[n], CAP);
        float u = bf2f(y[(size_t)n * 64 + lane]);
        u = gather16p(y, &csr2[n * CAP], dg, lane, u);
        zs[(wave * 16 + j) * LSTR + lane] = f2bf(fmaxf(u + b1v, 0.f));
    }
    f32x4 acc[4];
#pragma unroll
    for (int c = 0; c < 4; ++c) acc[c] = (f32x4){0.f, 0.f, 0.f, 0.f};
    const bf16x8 a0 = *reinterpret_cast<const bf16x8*>(&zs[(wave * 16 + m) * LSTR + q * 8]);
    const bf16x8 a1 = *reinterpret_cast<const bf16x8*>(&zs[(wave * 16 + m) * LSTR + 32 + q * 8]);
#pragma unroll
    for (int c = 0; c < 4; ++c) {
        const bf16x8 bb0 = *reinterpret_cast<const bf16x8*>(&w2T[(c * 16 + m) * 64 + q * 8]);
        const bf16x8 bb1 = *reinterpret_cast<const bf16x8*>(&w2T[(c * 16 + m) * 64 + 32 + q * 8]);
        acc[c] = __builtin_amdgcn_mfma_f32_16x16x32_bf16(a0, bb0, acc[c], 0, 0, 0);
        acc[c] = __builtin_amdgcn_mfma_f32_16x16x32_bf16(a1, bb1, acc[c], 0, 0, 0);
    }
#pragma unroll
    for (int c = 0; c < 4; ++c) {
        const float bb = b2[c * 16 + m];
#pragma unroll
        for (int r = 0; r < 4; ++r) {
            const int n = n0 + wave * 16 + q * 4 + r;
            if (n < N_NODES) hout[(size_t)n * 64 + c * 16 + m] = f2bf(fmaxf(acc[c][r] + bb, 0.f));
        }
    }
}

// shared body for full GIN layer (barrier-free; global pre-transposed weights)
__device__ __forceinline__ void gin_mfma2(const u16* __restrict__ hin,
                                          const int* __restrict__ deg,
                                          const int* __restrict__ csr2,
                                          const u16* __restrict__ w1T,
                                          const float* __restrict__ b1,
                                          const u16* __restrict__ w2T,
                                          u16* us, u16* zs,
                                          int n0, int t, f32x4 acc[4]) {
    const int lane = t & 63, wave = t >> 6;
    const int q = lane >> 4, m = lane & 15;
    const int base = n0 + wave * 16;
#pragma unroll 2
    for (int j = 0; j < 16; ++j) {
        const int n = min(base + j, N_NODES - 1);
        const int dg = min(deg[n], CAP);
        float u = bf2f(hin[(size_t)n * 64 + lane]);
        u = gather16p(hin, &csr2[n * CAP], dg, lane, u);
        us[(wave * 16 + j) * LSTR + lane] = f2bf(u);
    }
    f32x4 z[4];
#pragma unroll
    for (int c = 0; c < 4; ++c) z[c] = (f32x4){0.f, 0.f, 0.f, 0.f};
    {
        const bf16x8 a0 = *reinterpret_cast<const bf16x8*>(&us[(wave * 16 + m) * LSTR + q * 8]);
        const bf16x8 a1 = *reinterpret_cast<const bf16x8*>(&us[(wave * 16 + m) * LSTR + 32 + q * 8]);
#pragma unroll
        for (int c = 0; c < 4; ++c) {
            const bf16x8 bb0 = *reinterpret_cast<const bf16x8*>(&w1T[(c * 16 + m) * 64 + q * 8]);
            const bf16x8 bb1 = *reinterpret_cast<const bf16x8*>(&w1T[(c * 16 + m) * 64 + 32 + q * 8]);
            z[c] = __builtin_amdgcn_mfma_f32_16x16x32_bf16(a0, bb0, z[c], 0, 0, 0);
            z[c] = __builtin_amdgcn_mfma_f32_16x16x32_bf16(a1, bb1, z[c], 0, 0, 0);
        }
    }
    // z epilogue -> zs (own-wave rows only; no barrier needed)
#pragma unroll
    for (int c = 0; c < 4; ++c) {
        const float bb = b1[c * 16 + m];
#pragma unroll
        for (int r = 0; r < 4; ++r)
            zs[(wave * 16 + q * 4 + r) * LSTR + c * 16 + m] = f2bf(fmaxf(z[c][r] + bb, 0.f));
    }
#pragma unroll
    for (int c = 0; c < 4; ++c) acc[c] = (f32x4){0.f, 0.f, 0.f, 0.f};
    {
        const bf16x8 a0 = *reinterpret_cast<const bf16x8*>(&zs[(wave * 16 + m) * LSTR + q * 8]);
        const bf16x8 a1 = *reinterpret_cast<const bf16x8*>(&zs[(wave * 16 + m) * LSTR + 32 + q * 8]);
#pragma unroll
        for (int c = 0; c < 4; ++c) {
            const bf16x8 bb0 = *reinterpret_cast<const bf16x8*>(&w2T[(c * 16 + m) * 64 + q * 8]);
            const bf16x8 bb1 = *reinterpret_cast<const bf16x8*>(&w2T[(c * 16 + m) * 64 + 32 + q * 8]);
            acc[c] = __builtin_amdgcn_mfma_f32_16x16x32_bf16(a0, bb0, acc[c], 0, 0, 0);
            acc[c] = __builtin_amdgcn_mfma_f32_16x16x32_bf16(a1, bb1, acc[c], 0, 0, 0);
        }
    }
}

// ---------------- layer 1: h' -> global bf16 ----------------
__global__ __launch_bounds__(256, 4) void k_gin(const u16* __restrict__ hin,
                                                const int* __restrict__ deg,
                                                const int* __restrict__ csr2,
                                                const u16* __restrict__ w1T,
                                                const float* __restrict__ b1,
                                                const u16* __restrict__ w2T,
                                                const float* __restrict__ b2,
                                                u16* __restrict__ hout) {
    __shared__ u16 us[64 * LSTR];
    __shared__ u16 zs[64 * LSTR];
    const int t = threadIdx.x;
    const int lane = t & 63, wave = t >> 6;
    const int q = lane >> 4, m = lane & 15;
    const int n0 = blockIdx.x * 64;
    f32x4 acc[4];
    gin_mfma2(hin, deg, csr2, w1T, b1, w2T, us, zs, n0, t, acc);
#pragma unroll
    for (int c = 0; c < 4; ++c) {
        const float bb = b2[c * 16 + m];
#pragma unroll
        for (int r = 0; r < 4; ++r) {
            const int n = n0 + wave * 16 + q * 4 + r;
            if (n < N_NODES) hout[(size_t)n * 64 + c * 16 + m] = f2bf(fmaxf(acc[c][r] + bb, 0.f));
        }
    }
}

// ---------------- layer 2 fused with mean-pool numerator (sorted batch_ids) ------
__global__ __launch_bounds__(256, 4) void k_gin_pool(const u16* __restrict__ hin,
                                                     const int* __restrict__ deg,
                                                     const int* __restrict__ csr2,
                                                     const u16* __restrict__ w1T,
                                                     const float* __restrict__ b1,
                                                     const u16* __restrict__ w2T,
                                                     const float* __restrict__ b2,
                                                     const int* __restrict__ bids,
                                                     float* __restrict__ pooled) {
    __shared__ u16 us[64 * LSTR];
    __shared__ u16 zs[64 * LSTR];
    const int t = threadIdx.x;
    const int lane = t & 63, wave = t >> 6;
    const int q = lane >> 4, m = lane & 15;
    const int n0 = blockIdx.x * 64;
    f32x4 acc[4];
    gin_mfma2(hin, deg, csr2, w1T, b1, w2T, us, zs, n0, t, acc);
    // store h into us (own-wave rows), then run-length segmented atomics
#pragma unroll
    for (int c = 0; c < 4; ++c) {
        const float bb = b2[c * 16 + m];
#pragma unroll
        for (int r = 0; r < 4; ++r)
            us[(wave * 16 + q * 4 + r) * LSTR + c * 16 + m] = f2bf(fmaxf(acc[c][r] + bb, 0.f));
    }
    const int base = n0 + wave * 16;
    if (base < N_NODES) {
        float s = 0.f;
        int cur = bids[base];
        for (int j = 0; j < 16; ++j) {
            const int n = base + j;
            if (n >= N_NODES) break;   // wave-uniform
            const int b = bids[n];
            const float h = bf2f(us[(wave * 16 + j) * LSTR + lane]);
            if (b != cur) {
                atomicAdd(&pooled[cur * 64 + lane], s);
                cur = b; s = h;
            } else {
                s += h;
            }
        }
        atomicAdd(&pooled[cur * 64 + lane], s);
    }
}

// ---------------- A[:, 0:512] = bf16((pooled/cnt) @ lin_w + lin_b) ----------------
__global__ __launch_bounds__(256) void k_emb(const float* __restrict__ pooled,
                                             const float* __restrict__ counts,
                                             const float* __restrict__ lw,
                                             const float* __restrict__ lb,
                                             u16* __restrict__ A) {
    __shared__ float prow[8][64];
    const int b0 = blockIdx.x * 8;
    const int t = threadIdx.x;
    const int lane = t & 63, wave = t >> 6;
    for (int i = 0; i < 2; ++i) {
        const int r = i * 4 + wave;
        const int b = b0 + r;
        const float c = fmaxf(counts[b], 1.0f);
        prow[r][lane] = pooled[b * 64 + lane] / c;
    }
    __syncthreads();
    for (int o = t; o < 512; o += 256) {
        float acc[8];
#pragma unroll
        for (int r = 0; r < 8; ++r) acc[r] = lb[o];
        for (int k = 0; k < 64; ++k) {
            const float wv = lw[k * 512 + o];
#pragma unroll
            for (int r = 0; r < 8; ++r) acc[r] += prow[r][k] * wv;
        }
#pragma unroll
        for (int r = 0; r < 8; ++r) A[(size_t)(b0 + r) * AIN + o] = f2bf(acc[r]);
    }
}

// ---------------- out = A @ final_w + final_b — MFMA ([4000,1112]@[1112,512]) ----
__global__ __launch_bounds__(256) void k_final(const u16* __restrict__ A,
                                               const u16* __restrict__ fwT,
                                               const float* __restrict__ fb,
                                               float* __restrict__ out) {
    __shared__ u16 as[64 * 40];
    const int t = threadIdx.x;
    const int lane = t & 63, wave = t >> 6;
    const int q = lane >> 4, m = lane & 15;
    const int r0 = blockIdx.x * 64, c0 = blockIdx.y * 64;

    f32x4 acc[4];
#pragma unroll
    for (int c = 0; c < 4; ++c) acc[c] = (f32x4){0.f, 0.f, 0.f, 0.f};

    const int row = t >> 2, seg = t & 3;
    for (int k0 = 0; k0 < 1120; k0 += 32) {
        const int gr = r0 + row, gk = k0 + seg * 8;
        uint4 v = {0u, 0u, 0u, 0u};
        if (gr < BGRAPH && gk < AIN)
            v = *reinterpret_cast<const uint4*>(&A[(size_t)gr * AIN + gk]);
        *reinterpret_cast<uint4*>(&as[row * 40 + seg * 8]) = v;
        __syncthreads();
        const bf16x8 a = *reinterpret_cast<const bf16x8*>(&as[(wave * 16 + m) * 40 + q * 8]);
#pragma unroll
        for (int c = 0; c < 4; ++c) {
            const bf16x8 b = *reinterpret_cast<const bf16x8*>(&fwT[(size_t)(c0 + c * 16 + m) * 1120 + k0 + q * 8]);
            acc[c] = __builtin_amdgcn_mfma_f32_16x16x32_bf16(a, b, acc[c], 0, 0, 0);
        }
        __syncthreads();
    }
#pragma unroll
    for (int c = 0; c < 4; ++c) {
        const float bb = fb[c0 + c * 16 + m];
#pragma unroll
        for (int r = 0; r < 4; ++r) {
            const int rr = r0 + wave * 16 + q * 4 + r;
            if (rr < BGRAPH) out[(size_t)rr * 512 + c0 + c * 16 + m] = acc[c][r] + bb;
        }
    }
}

extern "C" void kernel_launch(void* const* d_in, const int* in_sizes, int n_in,
                              void* d_out, int out_size, void* d_ws, size_t ws_size,
                              hipStream_t stream) {
    const int*   pred_pairs = (const int*)d_in[0];
    const float* x          = (const float*)d_in[1];
    const int*   ei         = (const int*)d_in[2];
    const int*   bids       = (const int*)d_in[3];
    const float* ee         = (const float*)d_in[4];
    const float* w1_0 = (const float*)d_in[5];
    const float* b1_0 = (const float*)d_in[6];
    const float* w2_0 = (const float*)d_in[7];
    const float* b2_0 = (const float*)d_in[8];
    const float* w1_1 = (const float*)d_in[9];
    const float* b1_1 = (const float*)d_in[10];
    const float* w2_1 = (const float*)d_in[11];
    const float* b2_1 = (const float*)d_in[12];
    const float* w1_2 = (const float*)d_in[13];
    const float* b1_2 = (const float*)d_in[14];
    const float* w2_2 = (const float*)d_in[15];
    const float* b2_2 = (const float*)d_in[16];
    const float* lin_w   = (const float*)d_in[17];
    const float* lin_b   = (const float*)d_in[18];
    const float* final_w = (const float*)d_in[19];
    const float* final_b = (const float*)d_in[20];
    float* out = (float*)d_out;

    // workspace layout (16-B aligned regions)
    u16*   Y      = (u16*)d_ws;                          // 6,400,000 u16
    u16*   Hb     = Y + (size_t)N_NODES * 64;            // 6,400,000 u16
    int*   csr2   = (int*)(Hb + (size_t)N_NODES * 64);   // 4,800,000 int
    int*   deg    = csr2 + (size_t)N_NODES * CAP;        // 100,000 int
    float* pooled = (float*)(deg + N_NODES);             // 256,000 f
    float* counts = pooled + (size_t)BGRAPH * 64;        // 4,000 f
    u16*   A      = (u16*)(counts + BGRAPH);             // 4,448,000 u16
    u16*   w0T    = A + (size_t)BGRAPH * AIN;            // 28,672 u16
    u16*   fwT    = w0T + 64 * 448;                      // 573,440 u16
    u16*   wT5    = fwT + (size_t)512 * 1120;            // 5 x 4096 u16: w2T0,w1T1,w2T1,w1T2,w2T2
    u16*   w2T0   = wT5;
    u16*   w1T1   = w2T0 + 4096;
    u16*   w2T1   = w1T1 + 4096;
    u16*   w1T2   = w2T1 + 4096;
    u16*   w2T2   = w1T2 + 4096;

    // zero deg + pooled + counts (adjacent)
    hipMemsetAsync(deg, 0, (size_t)(N_NODES + BGRAPH * 64 + BGRAPH) * sizeof(int), stream);

    k_prep_all<<<(PREP_TOT + 255) / 256, 256, 0, stream>>>(
        w1_0, final_w, w2_0, w1_1, w2_1, w1_2, w2_2, pred_pairs, ee,
        w0T, fwT, wT5, A);
    k_graph<<<(N_EDGES + 255) / 256, 256, 0, stream>>>(ei, deg, csr2, bids, counts);
    k_gemm_xw<<<(N_NODES + 63) / 64, 256, 0, stream>>>(x, w0T, Y);
    k_gin0<<<(N_NODES + 63) / 64, 256, 0, stream>>>(Y, deg, csr2, b1_0, w2T0, b2_0, Hb);
    k_gin<<<(N_NODES + 63) / 64, 256, 0, stream>>>(Hb, deg, csr2, w1T1, b1_1, w2T1, b2_1, Y);
    k_gin_pool<<<(N_NODES + 63) / 64, 256, 0, stream>>>(Y, deg, csr2, w1T2, b1_2, w2T2, b2_2, bids, pooled);
    k_emb<<<BGRAPH / 8, 256, 0, stream>>>(pooled, counts, lin_w, lin_b, A);
    k_final<<<dim3((BGRAPH + 63) / 64, 8), 256, 0, stream>>>(A, fwT, final_b, out);
}

// Round 6
// 560.054 us; speedup vs baseline: 1.0936x; 1.0936x over previous
//
#include <hip/hip_runtime.h>
#include <hip/hip_bf16.h>

#define N_NODES 100000
#define N_EDGES 800000
#define BGRAPH  4000
#define GNN_IN  428
#define HDIM    64
#define HID     512
#define EMBD    300
#define AIN     1112   // 512 + 600
#define CAP     48     // max in-degree capacity (Poisson(8); actual max ~30)
#define LSTR    72     // LDS row stride (ushorts): 2-way bank alias only (free, m136)
#define XSTR    456    // k_gemm_xw LDS row stride (u16): word-stride 228 % 32 == 4 -> 2-way alias (free)

typedef unsigned short u16;
typedef short bf16x8 __attribute__((ext_vector_type(8)));   // MFMA A/B frag (8 bf16, 4 VGPRs)
typedef float f32x4  __attribute__((ext_vector_type(4)));   // MFMA C/D frag

__device__ __forceinline__ u16 f2bf(float f) {
    union { float f; unsigned int u; } v; v.f = f;
    unsigned int r = v.u + 0x7FFFu + ((v.u >> 16) & 1u);    // RNE
    return (u16)(r >> 16);
}
__device__ __forceinline__ float bf2f(u16 u) {
    union { unsigned int u; float f; } v; v.u = ((unsigned int)u) << 16;
    return v.f;
}

// ---------------- merged prep (FRAGMENT-PACKED weights) ----------------
// All weight tables are stored in MFMA-fragment order so that every wave B-load
// is lane-contiguous (1 KB coalesced) instead of 16-row scattered (16 cache
// lines per instruction -> TA serialization, the r1-r4 ~110us gemm invariant).
// Layout: fragment f occupies 512 u16; element (lane, j) at f*512 + lane*8 + j
// holds W[k][n] with q=lane>>4, m=lane&15, k=k0(f)+q*8+j, n=n0(f)+m.
#define R_W0T   (64 * 448)          // 28672  = 56 frags (tt*4+c)
#define R_FWT   (512 * 1120)        // 573440 = 1120 frags ((c0b*35+tt)*4+c)
#define R_W64   (5 * 4096)          // 20480  = 5 x 8 frags (kk*4+c)
#define R_ORIG  (BGRAPH * 600)      // 2400000
#define PREP_TOT (R_W0T + R_FWT + R_W64 + R_ORIG)

__global__ void k_prep_all(const float* __restrict__ w1_0, const float* __restrict__ final_w,
                           const float* __restrict__ w2_0, const float* __restrict__ w1_1,
                           const float* __restrict__ w2_1, const float* __restrict__ w1_2,
                           const float* __restrict__ w2_2,
                           const int* __restrict__ pp, const float* __restrict__ ee,
                           u16* __restrict__ w0T, u16* __restrict__ fwT,
                           u16* __restrict__ wT5, u16* __restrict__ A) {
    int idx = blockIdx.x * 256 + threadIdx.x;
    if (idx < R_W0T) {  // w0 frag-pack: frag = tt*4+c
        const int frag = idx >> 9, lane = (idx >> 3) & 63, j = idx & 7;
        const int tt = frag >> 2, c = frag & 3;
        const int q = lane >> 4, m = lane & 15;
        const int k = tt * 32 + q * 8 + j, n = c * 16 + m;
        w0T[idx] = (k < GNN_IN) ? f2bf(w1_0[k * 64 + n]) : (u16)0;
        return;
    }
    idx -= R_W0T;
    if (idx < R_FWT) {  // final_w frag-pack: frag = (c0b*35+tt)*4+c
        const int frag = idx >> 9, lane = (idx >> 3) & 63, j = idx & 7;
        const int c0b = frag / 140, rem = frag - c0b * 140;
        const int tt = rem >> 2, c = rem & 3;
        const int q = lane >> 4, m = lane & 15;
        const int k = tt * 32 + q * 8 + j, n = c0b * 64 + c * 16 + m;
        fwT[idx] = (k < AIN) ? f2bf(final_w[(size_t)k * 512 + n]) : (u16)0;
        return;
    }
    idx -= R_FWT;
    if (idx < R_W64) {  // five 64x64 frag-packs: order w2_0, w1_1, w2_1, w1_2, w2_2
        const int which = idx >> 12;
        const int r = idx & 4095;
        const float* w = (which == 0) ? w2_0 : (which == 1) ? w1_1
                       : (which == 2) ? w2_1 : (which == 3) ? w1_2 : w2_2;
        const int frag = r >> 9, lane = (r >> 3) & 63, j = r & 7;
        const int kk = frag >> 2, c = frag & 3;
        const int q = lane >> 4, m = lane & 15;
        const int k = kk * 32 + q * 8 + j, n = c * 16 + m;
        wT5[(which << 12) + r] = f2bf(w[k * 64 + n]);
        return;
    }
    idx -= R_W64;
    if (idx < R_ORIG) { // A[:, 512:1112] = bf16(entity_embed[pred_pairs])
        const int b = idx / 600;
        const int j = idx - b * 600;
        const int which = (j >= 300) ? 1 : 0;
        const int cls = pp[b * 2 + which];
        A[(size_t)b * AIN + 512 + j] = f2bf(ee[cls * 300 + (j - which * 300)]);
    }
}

// ---------------- merged CSR fill + segment counts ----------------
__global__ void k_graph(const int* __restrict__ ei, int* __restrict__ deg,
                        int* __restrict__ csr2,
                        const int* __restrict__ bids, float* __restrict__ counts) {
    const int e = blockIdx.x * blockDim.x + threadIdx.x;
    if (e < N_EDGES) {
        const int s = ei[e];
        const int d = ei[N_EDGES + e];
        const int slot = atomicAdd(&deg[d], 1);
        if (slot < CAP) csr2[d * CAP + slot] = s;
    }
    if (e < N_NODES) {
        atomicAdd(&counts[bids[e]], 1.0f);
    }
}

// ---------------- y = bf16(x @ w1_0) — coalesced LDS staging + frag-packed B ----
__global__ __launch_bounds__(256) void k_gemm_xw(const float* __restrict__ x,
                                                 const u16* __restrict__ w0T,
                                                 u16* __restrict__ y) {
    __shared__ u16 xs[64 * XSTR];
    const int t = threadIdx.x;
    const int lane = t & 63, wave = t >> 6;
    const int q = lane >> 4, m = lane & 15;
    const int n0 = blockIdx.x * 64;

    // zero pad cols 428..447 (read by the tt=13 fragment)
    for (int i = t; i < 64 * 20; i += 256) {
        const int r = i / 20, c = 428 + (i - r * 20);
        xs[r * XSTR + c] = 0;
    }
    // stage 64 rows x 428 cols (6848 float4s, contiguous in x), convert to bf16
#pragma unroll
    for (int i = 0; i < 27; ++i) {
        const int idx4 = t + i * 256;
        if (idx4 < 6848) {
            const int r = idx4 / 107, c4 = idx4 - r * 107;   // 428/4 = 107 float4 per row
            const int gr = min(n0 + r, N_NODES - 1);
            const float4 v = *reinterpret_cast<const float4*>(&x[(size_t)gr * GNN_IN + c4 * 4]);
            ushort4 o;
            o.x = f2bf(v.x); o.y = f2bf(v.y); o.z = f2bf(v.z); o.w = f2bf(v.w);
            *reinterpret_cast<ushort4*>(&xs[r * XSTR + c4 * 4]) = o;
        }
    }
    __syncthreads();

    f32x4 acc[4];
#pragma unroll
    for (int c = 0; c < 4; ++c) acc[c] = (f32x4){0.f, 0.f, 0.f, 0.f};

#pragma unroll
    for (int tt = 0; tt < 14; ++tt) {
        const int ka = tt * 32 + q * 8;
        const bf16x8 a = *reinterpret_cast<const bf16x8*>(&xs[(wave * 16 + m) * XSTR + ka]);
#pragma unroll
        for (int c = 0; c < 4; ++c) {
            const bf16x8 b = *reinterpret_cast<const bf16x8*>(&w0T[(((tt << 2) + c) << 9) + lane * 8]);
            acc[c] = __builtin_amdgcn_mfma_f32_16x16x32_bf16(a, b, acc[c], 0, 0, 0);
        }
    }

    // C-layout: col = c*16 + m, row-in-tile = q*4 + r
#pragma unroll
    for (int c = 0; c < 4; ++c)
#pragma unroll
        for (int r = 0; r < 4; ++r) {
            const int rr = n0 + wave * 16 + q * 4 + r;
            if (rr < N_NODES) y[(size_t)rr * 64 + c * 16 + m] = f2bf(acc[c][r]);
        }
}

// fixed-16 predicated gather (deg>16 tail is the <1% Poisson tail), fp32 accumulate
__device__ __forceinline__ float gather16p(const u16* __restrict__ hin,
                                           const int* __restrict__ lst,
                                           int dg, int lane, float u) {
    const int4* l4 = reinterpret_cast<const int4*>(lst);
    const int4 ia = l4[0], ib = l4[1], ic = l4[2], id4 = l4[3];
    int id[16] = {ia.x, ia.y, ia.z, ia.w, ib.x, ib.y, ib.z, ib.w,
                  ic.x, ic.y, ic.z, ic.w, id4.x, id4.y, id4.z, id4.w};
    float v[16];
#pragma unroll
    for (int i = 0; i < 16; ++i) {
        const bool ok = (i < dg);
        const int idx = ok ? id[i] : 0;
        v[i] = bf2f(hin[(size_t)idx * 64 + lane]) * (ok ? 1.f : 0.f);
    }
#pragma unroll
    for (int i = 0; i < 16; ++i) u += v[i];
    if (__builtin_expect(dg > 16, 0)) {
        for (int e = 16; e < dg; e += 8) {
            const int4 a = l4[e >> 2];
            const int4 b = l4[(e >> 2) + 1];
            int id2[8] = {a.x, a.y, a.z, a.w, b.x, b.y, b.z, b.w};
#pragma unroll
            for (int i = 0; i < 8; ++i) {
                const bool ok = (e + i < dg);
                const int idx = ok ? id2[i] : 0;
                u += bf2f(hin[(size_t)idx * 64 + lane]) * (ok ? 1.f : 0.f);
            }
        }
    }
    return u;
}

// ---------------- layer 0 (w1 pre-applied): h = relu(relu(u+b1) @ w2 + b2) ----------
// Barrier-free: LDS rows are wave-private. Weights frag-packed (coalesced loads).
__global__ __launch_bounds__(256, 4) void k_gin0(const u16* __restrict__ y,
                                                 const int* __restrict__ deg,
                                                 const int* __restrict__ csr2,
                                                 const float* __restrict__ b1,
                                                 const u16* __restrict__ w2T,
                                                 const float* __restrict__ b2,
                                                 u16* __restrict__ hout) {
    __shared__ u16 zs[64 * LSTR];
    const int t = threadIdx.x;
    const int lane = t & 63, wave = t >> 6;
    const int q = lane >> 4, m = lane & 15;
    const int n0 = blockIdx.x * 64;
    const int base = n0 + wave * 16;
    const float b1v = b1[lane];
#pragma unroll 2
    for (int j = 0; j < 16; ++j) {
        const int n = min(base + j, N_NODES - 1);
        const int dg = min(deg[n], CAP);
        float u = bf2f(y[(size_t)n * 64 + lane]);
        u = gather16p(y, &csr2[n * CAP], dg, lane, u);
        zs[(wave * 16 + j) * LSTR + lane] = f2bf(fmaxf(u + b1v, 0.f));
    }
    f32x4 acc[4];
#pragma unroll
    for (int c = 0; c < 4; ++c) acc[c] = (f32x4){0.f, 0.f, 0.f, 0.f};
    const bf16x8 a0 = *reinterpret_cast<const bf16x8*>(&zs[(wave * 16 + m) * LSTR + q * 8]);
    const bf16x8 a1 = *reinterpret_cast<const bf16x8*>(&zs[(wave * 16 + m) * LSTR + 32 + q * 8]);
#pragma unroll
    for (int c = 0; c < 4; ++c) {
        const bf16x8 bb0 = *reinterpret_cast<const bf16x8*>(&w2T[((0 + c) << 9) + lane * 8]);
        const bf16x8 bb1 = *reinterpret_cast<const bf16x8*>(&w2T[((4 + c) << 9) + lane * 8]);
        acc[c] = __builtin_amdgcn_mfma_f32_16x16x32_bf16(a0, bb0, acc[c], 0, 0, 0);
        acc[c] = __builtin_amdgcn_mfma_f32_16x16x32_bf16(a1, bb1, acc[c], 0, 0, 0);
    }
#pragma unroll
    for (int c = 0; c < 4; ++c) {
        const float bb = b2[c * 16 + m];
#pragma unroll
        for (int r = 0; r < 4; ++r) {
            const int n = n0 + wave * 16 + q * 4 + r;
            if (n < N_NODES) hout[(size_t)n * 64 + c * 16 + m] = f2bf(fmaxf(acc[c][r] + bb, 0.f));
        }
    }
}

// shared body for full GIN layer (barrier-free; frag-packed weights)
__device__ __forceinline__ void gin_mfma2(const u16* __restrict__ hin,
                                          const int* __restrict__ deg,
                                          const int* __restrict__ csr2,
                                          const u16* __restrict__ w1T,
                                          const float* __restrict__ b1,
                                          const u16* __restrict__ w2T,
                                          u16* us, u16* zs,
                                          int n0, int t, f32x4 acc[4]) {
    const int lane = t & 63, wave = t >> 6;
    const int q = lane >> 4, m = lane & 15;
    const int base = n0 + wave * 16;
#pragma unroll 2
    for (int j = 0; j < 16; ++j) {
        const int n = min(base + j, N_NODES - 1);
        const int dg = min(deg[n], CAP);
        float u = bf2f(hin[(size_t)n * 64 + lane]);
        u = gather16p(hin, &csr2[n * CAP], dg, lane, u);
        us[(wave * 16 + j) * LSTR + lane] = f2bf(u);
    }
    f32x4 z[4];
#pragma unroll
    for (int c = 0; c < 4; ++c) z[c] = (f32x4){0.f, 0.f, 0.f, 0.f};
    {
        const bf16x8 a0 = *reinterpret_cast<const bf16x8*>(&us[(wave * 16 + m) * LSTR + q * 8]);
        const bf16x8 a1 = *reinterpret_cast<const bf16x8*>(&us[(wave * 16 + m) * LSTR + 32 + q * 8]);
#pragma unroll
        for (int c = 0; c < 4; ++c) {
            const bf16x8 bb0 = *reinterpret_cast<const bf16x8*>(&w1T[((0 + c) << 9) + lane * 8]);
            const bf16x8 bb1 = *reinterpret_cast<const bf16x8*>(&w1T[((4 + c) << 9) + lane * 8]);
            z[c] = __builtin_amdgcn_mfma_f32_16x16x32_bf16(a0, bb0, z[c], 0, 0, 0);
            z[c] = __builtin_amdgcn_mfma_f32_16x16x32_bf16(a1, bb1, z[c], 0, 0, 0);
        }
    }
    // z epilogue -> zs (own-wave rows only; no barrier needed)
#pragma unroll
    for (int c = 0; c < 4; ++c) {
        const float bb = b1[c * 16 + m];
#pragma unroll
        for (int r = 0; r < 4; ++r)
            zs[(wave * 16 + q * 4 + r) * LSTR + c * 16 + m] = f2bf(fmaxf(z[c][r] + bb, 0.f));
    }
#pragma unroll
    for (int c = 0; c < 4; ++c) acc[c] = (f32x4){0.f, 0.f, 0.f, 0.f};
    {
        const bf16x8 a0 = *reinterpret_cast<const bf16x8*>(&zs[(wave * 16 + m) * LSTR + q * 8]);
        const bf16x8 a1 = *reinterpret_cast<const bf16x8*>(&zs[(wave * 16 + m) * LSTR + 32 + q * 8]);
#pragma unroll
        for (int c = 0; c < 4; ++c) {
            const bf16x8 bb0 = *reinterpret_cast<const bf16x8*>(&w2T[((0 + c) << 9) + lane * 8]);
            const bf16x8 bb1 = *reinterpret_cast<const bf16x8*>(&w2T[((4 + c) << 9) + lane * 8]);
            acc[c] = __builtin_amdgcn_mfma_f32_16x16x32_bf16(a0, bb0, acc[c], 0, 0, 0);
            acc[c] = __builtin_amdgcn_mfma_f32_16x16x32_bf16(a1, bb1, acc[c], 0, 0, 0);
        }
    }
}

// ---------------- layer 1: h' -> global bf16 ----------------
__global__ __launch_bounds__(256, 4) void k_gin(const u16* __restrict__ hin,
                                                const int* __restrict__ deg,
                                                const int* __restrict__ csr2,
                                                const u16* __restrict__ w1T,
                                                const float* __restrict__ b1,
                                                const u16* __restrict__ w2T,
                                                const float* __restrict__ b2,
                                                u16* __restrict__ hout) {
    __shared__ u16 us[64 * LSTR];
    __shared__ u16 zs[64 * LSTR];
    const int t = threadIdx.x;
    const int lane = t & 63, wave = t >> 6;
    const int q = lane >> 4, m = lane & 15;
    const int n0 = blockIdx.x * 64;
    f32x4 acc[4];
    gin_mfma2(hin, deg, csr2, w1T, b1, w2T, us, zs, n0, t, acc);
#pragma unroll
    for (int c = 0; c < 4; ++c) {
        const float bb = b2[c * 16 + m];
#pragma unroll
        for (int r = 0; r < 4; ++r) {
            const int n = n0 + wave * 16 + q * 4 + r;
            if (n < N_NODES) hout[(size_t)n * 64 + c * 16 + m] = f2bf(fmaxf(acc[c][r] + bb, 0.f));
        }
    }
}

// ---------------- layer 2 fused with mean-pool numerator (sorted batch_ids) ------
__global__ __launch_bounds__(256, 4) void k_gin_pool(const u16* __restrict__ hin,
                                                     const int* __restrict__ deg,
                                                     const int* __restrict__ csr2,
                                                     const u16* __restrict__ w1T,
                                                     const float* __restrict__ b1,
                                                     const u16* __restrict__ w2T,
                                                     const float* __restrict__ b2,
                                                     const int* __restrict__ bids,
                                                     float* __restrict__ pooled) {
    __shared__ u16 us[64 * LSTR];
    __shared__ u16 zs[64 * LSTR];
    const int t = threadIdx.x;
    const int lane = t & 63, wave = t >> 6;
    const int q = lane >> 4, m = lane & 15;
    const int n0 = blockIdx.x * 64;
    f32x4 acc[4];
    gin_mfma2(hin, deg, csr2, w1T, b1, w2T, us, zs, n0, t, acc);
    // store h into us (own-wave rows), then run-length segmented atomics
#pragma unroll
    for (int c = 0; c < 4; ++c) {
        const float bb = b2[c * 16 + m];
#pragma unroll
        for (int r = 0; r < 4; ++r)
            us[(wave * 16 + q * 4 + r) * LSTR + c * 16 + m] = f2bf(fmaxf(acc[c][r] + bb, 0.f));
    }
    const int base = n0 + wave * 16;
    if (base < N_NODES) {
        float s = 0.f;
        int cur = bids[base];
        for (int j = 0; j < 16; ++j) {
            const int n = base + j;
            if (n >= N_NODES) break;   // wave-uniform
            const int b = bids[n];
            const float h = bf2f(us[(wave * 16 + j) * LSTR + lane]);
            if (b != cur) {
                atomicAdd(&pooled[cur * 64 + lane], s);
                cur = b; s = h;
            } else {
                s += h;
            }
        }
        atomicAdd(&pooled[cur * 64 + lane], s);
    }
}

// ---------------- A[:, 0:512] = bf16((pooled/cnt) @ lin_w + lin_b) ----------------
__global__ __launch_bounds__(256) void k_emb(const float* __restrict__ pooled,
                                             const float* __restrict__ counts,
                                             const float* __restrict__ lw,
                                             const float* __restrict__ lb,
                                             u16* __restrict__ A) {
    __shared__ float prow[8][64];
    const int b0 = blockIdx.x * 8;
    const int t = threadIdx.x;
    const int lane = t & 63, wave = t >> 6;
    for (int i = 0; i < 2; ++i) {
        const int r = i * 4 + wave;
        const int b = b0 + r;
        const float c = fmaxf(counts[b], 1.0f);
        prow[r][lane] = pooled[b * 64 + lane] / c;
    }
    __syncthreads();
    for (int o = t; o < 512; o += 256) {
        float acc[8];
#pragma unroll
        for (int r = 0; r < 8; ++r) acc[r] = lb[o];
        for (int k = 0; k < 64; ++k) {
            const float wv = lw[k * 512 + o];
#pragma unroll
            for (int r = 0; r < 8; ++r) acc[r] += prow[r][k] * wv;
        }
#pragma unroll
        for (int r = 0; r < 8; ++r) A[(size_t)(b0 + r) * AIN + o] = f2bf(acc[r]);
    }
}

// ---------------- out = A @ final_w + final_b — MFMA, frag-packed B ----
__global__ __launch_bounds__(256) void k_final(const u16* __restrict__ A,
                                               const u16* __restrict__ fwT,
                                               const float* __restrict__ fb,
                                               float* __restrict__ out) {
    __shared__ u16 as[64 * 40];
    const int t = threadIdx.x;
    const int lane = t & 63, wave = t >> 6;
    const int q = lane >> 4, m = lane & 15;
    const int r0 = blockIdx.x * 64, c0 = blockIdx.y * 64;

    f32x4 acc[4];
#pragma unroll
    for (int c = 0; c < 4; ++c) acc[c] = (f32x4){0.f, 0.f, 0.f, 0.f};

    const int row = t >> 2, seg = t & 3;
    for (int k0 = 0; k0 < 1120; k0 += 32) {
        const int tt = k0 >> 5;
        const int gr = r0 + row, gk = k0 + seg * 8;
        uint4 v = {0u, 0u, 0u, 0u};
        if (gr < BGRAPH && gk < AIN)
            v = *reinterpret_cast<const uint4*>(&A[(size_t)gr * AIN + gk]);
        *reinterpret_cast<uint4*>(&as[row * 40 + seg * 8]) = v;
        __syncthreads();
        const bf16x8 a = *reinterpret_cast<const bf16x8*>(&as[(wave * 16 + m) * 40 + q * 8]);
#pragma unroll
        for (int c = 0; c < 4; ++c) {
            const bf16x8 b = *reinterpret_cast<const bf16x8*>(
                &fwT[(size_t)((((blockIdx.y * 35 + tt) << 2) + c) << 9) + lane * 8]);
            acc[c] = __builtin_amdgcn_mfma_f32_16x16x32_bf16(a, b, acc[c], 0, 0, 0);
        }
        __syncthreads();
    }
#pragma unroll
    for (int c = 0; c < 4; ++c) {
        const float bb = fb[c0 + c * 16 + m];
#pragma unroll
        for (int r = 0; r < 4; ++r) {
            const int rr = r0 + wave * 16 + q * 4 + r;
            if (rr < BGRAPH) out[(size_t)rr * 512 + c0 + c * 16 + m] = acc[c][r] + bb;
        }
    }
}

extern "C" void kernel_launch(void* const* d_in, const int* in_sizes, int n_in,
                              void* d_out, int out_size, void* d_ws, size_t ws_size,
                              hipStream_t stream) {
    const int*   pred_pairs = (const int*)d_in[0];
    const float* x          = (const float*)d_in[1];
    const int*   ei         = (const int*)d_in[2];
    const int*   bids       = (const int*)d_in[3];
    const float* ee         = (const float*)d_in[4];
    const float* w1_0 = (const float*)d_in[5];
    const float* b1_0 = (const float*)d_in[6];
    const float* w2_0 = (const float*)d_in[7];
    const float* b2_0 = (const float*)d_in[8];
    const float* w1_1 = (const float*)d_in[9];
    const float* b1_1 = (const float*)d_in[10];
    const float* w2_1 = (const float*)d_in[11];
    const float* b2_1 = (const float*)d_in[12];
    const float* w1_2 = (const float*)d_in[13];
    const float* b1_2 = (const float*)d_in[14];
    const float* w2_2 = (const float*)d_in[15];
    const float* b2_2 = (const float*)d_in[16];
    const float* lin_w   = (const float*)d_in[17];
    const float* lin_b   = (const float*)d_in[18];
    const float* final_w = (const float*)d_in[19];
    const float* final_b = (const float*)d_in[20];
    float* out = (float*)d_out;

    // workspace layout (16-B aligned regions)
    u16*   Y      = (u16*)d_ws;                          // 6,400,000 u16
    u16*   Hb     = Y + (size_t)N_NODES * 64;            // 6,400,000 u16
    int*   csr2   = (int*)(Hb + (size_t)N_NODES * 64);   // 4,800,000 int
    int*   deg    = csr2 + (size_t)N_NODES * CAP;        // 100,000 int
    float* pooled = (float*)(deg + N_NODES);             // 256,000 f
    float* counts = pooled + (size_t)BGRAPH * 64;        // 4,000 f
    u16*   A      = (u16*)(counts + BGRAPH);             // 4,448,000 u16
    u16*   w0T    = A + (size_t)BGRAPH * AIN;            // 28,672 u16 (frag-packed)
    u16*   fwT    = w0T + 64 * 448;                      // 573,440 u16 (frag-packed)
    u16*   wT5    = fwT + (size_t)512 * 1120;            // 5 x 4096 u16 (frag-packed)
    u16*   w2T0   = wT5;
    u16*   w1T1   = w2T0 + 4096;
    u16*   w2T1   = w1T1 + 4096;
    u16*   w1T2   = w2T1 + 4096;
    u16*   w2T2   = w1T2 + 4096;

    // zero deg + pooled + counts (adjacent)
    hipMemsetAsync(deg, 0, (size_t)(N_NODES + BGRAPH * 64 + BGRAPH) * sizeof(int), stream);

    k_prep_all<<<(PREP_TOT + 255) / 256, 256, 0, stream>>>(
        w1_0, final_w, w2_0, w1_1, w2_1, w1_2, w2_2, pred_pairs, ee,
        w0T, fwT, wT5, A);
    k_graph<<<(N_EDGES + 255) / 256, 256, 0, stream>>>(ei, deg, csr2, bids, counts);
    k_gemm_xw<<<(N_NODES + 63) / 64, 256, 0, stream>>>(x, w0T, Y);
    k_gin0<<<(N_NODES + 63) / 64, 256, 0, stream>>>(Y, deg, csr2, b1_0, w2T0, b2_0, Hb);
    k_gin<<<(N_NODES + 63) / 64, 256, 0, stream>>>(Hb, deg, csr2, w1T1, b1_1, w2T1, b2_1, Y);
    k_gin_pool<<<(N_NODES + 63) / 64, 256, 0, stream>>>(Y, deg, csr2, w1T2, b1_2, w2T2, b2_2, bids, pooled);
    k_emb<<<BGRAPH / 8, 256, 0, stream>>>(pooled, counts, lin_w, lin_b, A);
    k_final<<<dim3((BGRAPH + 63) / 64, 8), 256, 0, stream>>>(A, fwT, final_b, out);
}

// Round 7
// 555.647 us; speedup vs baseline: 1.1023x; 1.0079x over previous
//
#include <hip/hip_runtime.h>
#include <hip/hip_bf16.h>

#define N_NODES 100000
#define N_EDGES 800000
#define BGRAPH  4000
#define GNN_IN  428
#define HDIM    64
#define HID     512
#define EMBD    300
#define AIN     1112   // 512 + 600
#define CAP     48     // max in-degree capacity (Poisson(8); actual max ~30)
#define LSTR    72     // LDS row stride (ushorts): 2-way bank alias only (free, m136)
#define XSTR    456    // k_gemm_xw LDS row stride (u16): word-stride 228 % 32 == 4 -> 2-way alias (free)

typedef unsigned short u16;
typedef short bf16x8 __attribute__((ext_vector_type(8)));   // MFMA A/B frag (8 bf16, 4 VGPRs)
typedef float f32x4  __attribute__((ext_vector_type(4)));   // MFMA C/D frag

__device__ __forceinline__ u16 f2bf(float f) {
    union { float f; unsigned int u; } v; v.f = f;
    unsigned int r = v.u + 0x7FFFu + ((v.u >> 16) & 1u);    // RNE
    return (u16)(r >> 16);
}
__device__ __forceinline__ float bf2f(u16 u) {
    union { unsigned int u; float f; } v; v.u = ((unsigned int)u) << 16;
    return v.f;
}

// ---------------- merged prep (FRAGMENT-PACKED weights) ----------------
// All weight tables are stored in MFMA-fragment order so that every wave B-load
// is lane-contiguous (1 KB coalesced) instead of 16-row scattered (16 cache
// lines per instruction -> TA serialization, the r1-r4 ~110us gemm invariant;
// fixed r6: 612 -> 560 us).
// Layout: fragment f occupies 512 u16; element (lane, j) at f*512 + lane*8 + j
// holds W[k][n] with q=lane>>4, m=lane&15, k=k0(f)+q*8+j, n=n0(f)+m.
#define R_W0T   (64 * 448)          // 28672  = 56 frags (tt*4+c)
#define R_FWT   (512 * 1120)        // 573440 = 1120 frags ((c0b*35+tt)*4+c)
#define R_W64   (5 * 4096)          // 20480  = 5 x 8 frags (kk*4+c)
#define R_ORIG  (BGRAPH * 600)      // 2400000
#define PREP_TOT (R_W0T + R_FWT + R_W64 + R_ORIG)

__global__ void k_prep_all(const float* __restrict__ w1_0, const float* __restrict__ final_w,
                           const float* __restrict__ w2_0, const float* __restrict__ w1_1,
                           const float* __restrict__ w2_1, const float* __restrict__ w1_2,
                           const float* __restrict__ w2_2,
                           const int* __restrict__ pp, const float* __restrict__ ee,
                           u16* __restrict__ w0T, u16* __restrict__ fwT,
                           u16* __restrict__ wT5, u16* __restrict__ A) {
    int idx = blockIdx.x * 256 + threadIdx.x;
    if (idx < R_W0T) {  // w0 frag-pack: frag = tt*4+c
        const int frag = idx >> 9, lane = (idx >> 3) & 63, j = idx & 7;
        const int tt = frag >> 2, c = frag & 3;
        const int q = lane >> 4, m = lane & 15;
        const int k = tt * 32 + q * 8 + j, n = c * 16 + m;
        w0T[idx] = (k < GNN_IN) ? f2bf(w1_0[k * 64 + n]) : (u16)0;
        return;
    }
    idx -= R_W0T;
    if (idx < R_FWT) {  // final_w frag-pack: frag = (c0b*35+tt)*4+c
        const int frag = idx >> 9, lane = (idx >> 3) & 63, j = idx & 7;
        const int c0b = frag / 140, rem = frag - c0b * 140;
        const int tt = rem >> 2, c = rem & 3;
        const int q = lane >> 4, m = lane & 15;
        const int k = tt * 32 + q * 8 + j, n = c0b * 64 + c * 16 + m;
        fwT[idx] = (k < AIN) ? f2bf(final_w[(size_t)k * 512 + n]) : (u16)0;
        return;
    }
    idx -= R_FWT;
    if (idx < R_W64) {  // five 64x64 frag-packs: order w2_0, w1_1, w2_1, w1_2, w2_2
        const int which = idx >> 12;
        const int r = idx & 4095;
        const float* w = (which == 0) ? w2_0 : (which == 1) ? w1_1
                       : (which == 2) ? w2_1 : (which == 3) ? w1_2 : w2_2;
        const int frag = r >> 9, lane = (r >> 3) & 63, j = r & 7;
        const int kk = frag >> 2, c = frag & 3;
        const int q = lane >> 4, m = lane & 15;
        const int k = kk * 32 + q * 8 + j, n = c * 16 + m;
        wT5[(which << 12) + r] = f2bf(w[k * 64 + n]);
        return;
    }
    idx -= R_W64;
    if (idx < R_ORIG) { // A[:, 512:1112] = bf16(entity_embed[pred_pairs])
        const int b = idx / 600;
        const int j = idx - b * 600;
        const int which = (j >= 300) ? 1 : 0;
        const int cls = pp[b * 2 + which];
        A[(size_t)b * AIN + 512 + j] = f2bf(ee[cls * 300 + (j - which * 300)]);
    }
}

// ---------------- merged CSR fill + segment counts ----------------
__global__ void k_graph(const int* __restrict__ ei, int* __restrict__ deg,
                        int* __restrict__ csr2,
                        const int* __restrict__ bids, float* __restrict__ counts) {
    const int e = blockIdx.x * blockDim.x + threadIdx.x;
    if (e < N_EDGES) {
        const int s = ei[e];
        const int d = ei[N_EDGES + e];
        const int slot = atomicAdd(&deg[d], 1);
        if (slot < CAP) csr2[d * CAP + slot] = s;
    }
    if (e < N_NODES) {
        atomicAdd(&counts[bids[e]], 1.0f);
    }
}

// ---------------- y = bf16(x @ w1_0) — coalesced LDS staging + frag-packed B ----
__global__ __launch_bounds__(256) void k_gemm_xw(const float* __restrict__ x,
                                                 const u16* __restrict__ w0T,
                                                 u16* __restrict__ y) {
    __shared__ u16 xs[64 * XSTR];
    const int t = threadIdx.x;
    const int lane = t & 63, wave = t >> 6;
    const int q = lane >> 4, m = lane & 15;
    const int n0 = blockIdx.x * 64;

    // zero pad cols 428..447 (read by the tt=13 fragment)
    for (int i = t; i < 64 * 20; i += 256) {
        const int r = i / 20, c = 428 + (i - r * 20);
        xs[r * XSTR + c] = 0;
    }
    // stage 64 rows x 428 cols (6848 float4s, contiguous in x), convert to bf16
#pragma unroll
    for (int i = 0; i < 27; ++i) {
        const int idx4 = t + i * 256;
        if (idx4 < 6848) {
            const int r = idx4 / 107, c4 = idx4 - r * 107;   // 428/4 = 107 float4 per row
            const int gr = min(n0 + r, N_NODES - 1);
            const float4 v = *reinterpret_cast<const float4*>(&x[(size_t)gr * GNN_IN + c4 * 4]);
            ushort4 o;
            o.x = f2bf(v.x); o.y = f2bf(v.y); o.z = f2bf(v.z); o.w = f2bf(v.w);
            *reinterpret_cast<ushort4*>(&xs[r * XSTR + c4 * 4]) = o;
        }
    }
    __syncthreads();

    f32x4 acc[4];
#pragma unroll
    for (int c = 0; c < 4; ++c) acc[c] = (f32x4){0.f, 0.f, 0.f, 0.f};

#pragma unroll
    for (int tt = 0; tt < 14; ++tt) {
        const int ka = tt * 32 + q * 8;
        const bf16x8 a = *reinterpret_cast<const bf16x8*>(&xs[(wave * 16 + m) * XSTR + ka]);
#pragma unroll
        for (int c = 0; c < 4; ++c) {
            const bf16x8 b = *reinterpret_cast<const bf16x8*>(&w0T[(((tt << 2) + c) << 9) + lane * 8]);
            acc[c] = __builtin_amdgcn_mfma_f32_16x16x32_bf16(a, b, acc[c], 0, 0, 0);
        }
    }

    // C-layout: col = c*16 + m, row-in-tile = q*4 + r
#pragma unroll
    for (int c = 0; c < 4; ++c)
#pragma unroll
        for (int r = 0; r < 4; ++r) {
            const int rr = n0 + wave * 16 + q * 4 + r;
            if (rr < N_NODES) y[(size_t)rr * 64 + c * 16 + m] = f2bf(acc[c][r]);
        }
}

// wave-uniform chunk-8 gather: dg is identical across the wave (all lanes share n),
// so the chunk loop is a uniform s_cbranch (no divergence). Mean issued loads/node
// drops 16 -> ~9.7 for Poisson(8); within a chunk the 8 row-loads are independent.
__device__ __forceinline__ float gather8c(const u16* __restrict__ hin,
                                          const int* __restrict__ lst,
                                          int dg, int lane, float u) {
    const int4* l4 = reinterpret_cast<const int4*>(lst);
    for (int e = 0; e < dg; e += 8) {
        const int4 a = l4[e >> 2];
        const int4 b = l4[(e >> 2) + 1];
        int id[8] = {a.x, a.y, a.z, a.w, b.x, b.y, b.z, b.w};
        float v[8];
#pragma unroll
        for (int i = 0; i < 8; ++i) {
            const bool ok = (e + i < dg);
            const int idx = ok ? id[i] : 0;
            v[i] = bf2f(hin[(size_t)idx * 64 + lane]) * (ok ? 1.f : 0.f);
        }
#pragma unroll
        for (int i = 0; i < 8; ++i) u += v[i];
    }
    return u;
}

// ---------------- layer 0 (w1 pre-applied): h = relu(relu(u+b1) @ w2 + b2) ----------
// Barrier-free: LDS rows are wave-private. Weights frag-packed (coalesced loads).
__global__ __launch_bounds__(256, 4) void k_gin0(const u16* __restrict__ y,
                                                 const int* __restrict__ deg,
                                                 const int* __restrict__ csr2,
                                                 const float* __restrict__ b1,
                                                 const u16* __restrict__ w2T,
                                                 const float* __restrict__ b2,
                                                 u16* __restrict__ hout) {
    __shared__ u16 zs[64 * LSTR];
    const int t = threadIdx.x;
    const int lane = t & 63, wave = t >> 6;
    const int q = lane >> 4, m = lane & 15;
    const int n0 = blockIdx.x * 64;
    const int base = n0 + wave * 16;
    const float b1v = b1[lane];
#pragma unroll 2
    for (int j = 0; j < 16; ++j) {
        const int n = min(base + j, N_NODES - 1);
        const int dg = min(deg[n], CAP);
        float u = bf2f(y[(size_t)n * 64 + lane]);
        u = gather8c(y, &csr2[n * CAP], dg, lane, u);
        zs[(wave * 16 + j) * LSTR + lane] = f2bf(fmaxf(u + b1v, 0.f));
    }
    f32x4 acc[4];
#pragma unroll
    for (int c = 0; c < 4; ++c) acc[c] = (f32x4){0.f, 0.f, 0.f, 0.f};
    const bf16x8 a0 = *reinterpret_cast<const bf16x8*>(&zs[(wave * 16 + m) * LSTR + q * 8]);
    const bf16x8 a1 = *reinterpret_cast<const bf16x8*>(&zs[(wave * 16 + m) * LSTR + 32 + q * 8]);
#pragma unroll
    for (int c = 0; c < 4; ++c) {
        const bf16x8 bb0 = *reinterpret_cast<const bf16x8*>(&w2T[((0 + c) << 9) + lane * 8]);
        const bf16x8 bb1 = *reinterpret_cast<const bf16x8*>(&w2T[((4 + c) << 9) + lane * 8]);
        acc[c] = __builtin_amdgcn_mfma_f32_16x16x32_bf16(a0, bb0, acc[c], 0, 0, 0);
        acc[c] = __builtin_amdgcn_mfma_f32_16x16x32_bf16(a1, bb1, acc[c], 0, 0, 0);
    }
#pragma unroll
    for (int c = 0; c < 4; ++c) {
        const float bb = b2[c * 16 + m];
#pragma unroll
        for (int r = 0; r < 4; ++r) {
            const int n = n0 + wave * 16 + q * 4 + r;
            if (n < N_NODES) hout[(size_t)n * 64 + c * 16 + m] = f2bf(fmaxf(acc[c][r] + bb, 0.f));
        }
    }
}

// shared body for full GIN layer (barrier-free; frag-packed weights)
__device__ __forceinline__ void gin_mfma2(const u16* __restrict__ hin,
                                          const int* __restrict__ deg,
                                          const int* __restrict__ csr2,
                                          const u16* __restrict__ w1T,
                                          const float* __restrict__ b1,
                                          const u16* __restrict__ w2T,
                                          u16* us, u16* zs,
                                          int n0, int t, f32x4 acc[4]) {
    const int lane = t & 63, wave = t >> 6;
    const int q = lane >> 4, m = lane & 15;
    const int base = n0 + wave * 16;
#pragma unroll 2
    for (int j = 0; j < 16; ++j) {
        const int n = min(base + j, N_NODES - 1);
        const int dg = min(deg[n], CAP);
        float u = bf2f(hin[(size_t)n * 64 + lane]);
        u = gather8c(hin, &csr2[n * CAP], dg, lane, u);
        us[(wave * 16 + j) * LSTR + lane] = f2bf(u);
    }
    f32x4 z[4];
#pragma unroll
    for (int c = 0; c < 4; ++c) z[c] = (f32x4){0.f, 0.f, 0.f, 0.f};
    {
        const bf16x8 a0 = *reinterpret_cast<const bf16x8*>(&us[(wave * 16 + m) * LSTR + q * 8]);
        const bf16x8 a1 = *reinterpret_cast<const bf16x8*>(&us[(wave * 16 + m) * LSTR + 32 + q * 8]);
#pragma unroll
        for (int c = 0; c < 4; ++c) {
            const bf16x8 bb0 = *reinterpret_cast<const bf16x8*>(&w1T[((0 + c) << 9) + lane * 8]);
            const bf16x8 bb1 = *reinterpret_cast<const bf16x8*>(&w1T[((4 + c) << 9) + lane * 8]);
            z[c] = __builtin_amdgcn_mfma_f32_16x16x32_bf16(a0, bb0, z[c], 0, 0, 0);
            z[c] = __builtin_amdgcn_mfma_f32_16x16x32_bf16(a1, bb1, z[c], 0, 0, 0);
        }
    }
    // z epilogue -> zs (own-wave rows only; no barrier needed)
#pragma unroll
    for (int c = 0; c < 4; ++c) {
        const float bb = b1[c * 16 + m];
#pragma unroll
        for (int r = 0; r < 4; ++r)
            zs[(wave * 16 + q * 4 + r) * LSTR + c * 16 + m] = f2bf(fmaxf(z[c][r] + bb, 0.f));
    }
#pragma unroll
    for (int c = 0; c < 4; ++c) acc[c] = (f32x4){0.f, 0.f, 0.f, 0.f};
    {
        const bf16x8 a0 = *reinterpret_cast<const bf16x8*>(&zs[(wave * 16 + m) * LSTR + q * 8]);
        const bf16x8 a1 = *reinterpret_cast<const bf16x8*>(&zs[(wave * 16 + m) * LSTR + 32 + q * 8]);
#pragma unroll
        for (int c = 0; c < 4; ++c) {
            const bf16x8 bb0 = *reinterpret_cast<const bf16x8*>(&w2T[((0 + c) << 9) + lane * 8]);
            const bf16x8 bb1 = *reinterpret_cast<const bf16x8*>(&w2T[((4 + c) << 9) + lane * 8]);
            acc[c] = __builtin_amdgcn_mfma_f32_16x16x32_bf16(a0, bb0, acc[c], 0, 0, 0);
            acc[c] = __builtin_amdgcn_mfma_f32_16x16x32_bf16(a1, bb1, acc[c], 0, 0, 0);
        }
    }
}

// ---------------- layer 1: h' -> global bf16 ----------------
__global__ __launch_bounds__(256, 4) void k_gin(const u16* __restrict__ hin,
                                                const int* __restrict__ deg,
                                                const int* __restrict__ csr2,
                                                const u16* __restrict__ w1T,
                                                const float* __restrict__ b1,
                                                const u16* __restrict__ w2T,
                                                const float* __restrict__ b2,
                                                u16* __restrict__ hout) {
    __shared__ u16 us[64 * LSTR];
    __shared__ u16 zs[64 * LSTR];
    const int t = threadIdx.x;
    const int lane = t & 63, wave = t >> 6;
    const int q = lane >> 4, m = lane & 15;
    const int n0 = blockIdx.x * 64;
    f32x4 acc[4];
    gin_mfma2(hin, deg, csr2, w1T, b1, w2T, us, zs, n0, t, acc);
#pragma unroll
    for (int c = 0; c < 4; ++c) {
        const float bb = b2[c * 16 + m];
#pragma unroll
        for (int r = 0; r < 4; ++r) {
            const int n = n0 + wave * 16 + q * 4 + r;
            if (n < N_NODES) hout[(size_t)n * 64 + c * 16 + m] = f2bf(fmaxf(acc[c][r] + bb, 0.f));
        }
    }
}

// ---------------- layer 2 fused with mean-pool numerator (sorted batch_ids) ------
__global__ __launch_bounds__(256, 4) void k_gin_pool(const u16* __restrict__ hin,
                                                     const int* __restrict__ deg,
                                                     const int* __restrict__ csr2,
                                                     const u16* __restrict__ w1T,
                                                     const float* __restrict__ b1,
                                                     const u16* __restrict__ w2T,
                                                     const float* __restrict__ b2,
                                                     const int* __restrict__ bids,
                                                     float* __restrict__ pooled) {
    __shared__ u16 us[64 * LSTR];
    __shared__ u16 zs[64 * LSTR];
    const int t = threadIdx.x;
    const int lane = t & 63, wave = t >> 6;
    const int q = lane >> 4, m = lane & 15;
    const int n0 = blockIdx.x * 64;
    f32x4 acc[4];
    gin_mfma2(hin, deg, csr2, w1T, b1, w2T, us, zs, n0, t, acc);
    // store h into us (own-wave rows), then run-length segmented atomics
#pragma unroll
    for (int c = 0; c < 4; ++c) {
        const float bb = b2[c * 16 + m];
#pragma unroll
        for (int r = 0; r < 4; ++r)
            us[(wave * 16 + q * 4 + r) * LSTR + c * 16 + m] = f2bf(fmaxf(acc[c][r] + bb, 0.f));
    }
    const int base = n0 + wave * 16;
    if (base < N_NODES) {
        float s = 0.f;
        int cur = bids[base];
        for (int j = 0; j < 16; ++j) {
            const int n = base + j;
            if (n >= N_NODES) break;   // wave-uniform
            const int b = bids[n];
            const float h = bf2f(us[(wave * 16 + j) * LSTR + lane]);
            if (b != cur) {
                atomicAdd(&pooled[cur * 64 + lane], s);
                cur = b; s = h;
            } else {
                s += h;
            }
        }
        atomicAdd(&pooled[cur * 64 + lane], s);
    }
}

// ---------------- A[:, 0:512] = bf16((pooled/cnt) @ lin_w + lin_b) ----------------
__global__ __launch_bounds__(256) void k_emb(const float* __restrict__ pooled,
                                             const float* __restrict__ counts,
                                             const float* __restrict__ lw,
                                             const float* __restrict__ lb,
                                             u16* __restrict__ A) {
    __shared__ float prow[8][64];
    const int b0 = blockIdx.x * 8;
    const int t = threadIdx.x;
    const int lane = t & 63, wave = t >> 6;
    for (int i = 0; i < 2; ++i) {
        const int r = i * 4 + wave;
        const int b = b0 + r;
        const float c = fmaxf(counts[b], 1.0f);
        prow[r][lane] = pooled[b * 64 + lane] / c;
    }
    __syncthreads();
    for (int o = t; o < 512; o += 256) {
        float acc[8];
#pragma unroll
        for (int r = 0; r < 8; ++r) acc[r] = lb[o];
        for (int k = 0; k < 64; ++k) {
            const float wv = lw[k * 512 + o];
#pragma unroll
            for (int r = 0; r < 8; ++r) acc[r] += prow[r][k] * wv;
        }
#pragma unroll
        for (int r = 0; r < 8; ++r) A[(size_t)(b0 + r) * AIN + o] = f2bf(acc[r]);
    }
}

// ---------------- out = A @ final_w + final_b — MFMA, frag-packed B ----
__global__ __launch_bounds__(256) void k_final(const u16* __restrict__ A,
                                               const u16* __restrict__ fwT,
                                               const float* __restrict__ fb,
                                               float* __restrict__ out) {
    __shared__ u16 as[64 * 40];
    const int t = threadIdx.x;
    const int lane = t & 63, wave = t >> 6;
    const int q = lane >> 4, m = lane & 15;
    const int r0 = blockIdx.x * 64, c0 = blockIdx.y * 64;

    f32x4 acc[4];
#pragma unroll
    for (int c = 0; c < 4; ++c) acc[c] = (f32x4){0.f, 0.f, 0.f, 0.f};

    const int row = t >> 2, seg = t & 3;
    for (int k0 = 0; k0 < 1120; k0 += 32) {
        const int tt = k0 >> 5;
        const int gr = r0 + row, gk = k0 + seg * 8;
        uint4 v = {0u, 0u, 0u, 0u};
        if (gr < BGRAPH && gk < AIN)
            v = *reinterpret_cast<const uint4*>(&A[(size_t)gr * AIN + gk]);
        *reinterpret_cast<uint4*>(&as[row * 40 + seg * 8]) = v;
        __syncthreads();
        const bf16x8 a = *reinterpret_cast<const bf16x8*>(&as[(wave * 16 + m) * 40 + q * 8]);
#pragma unroll
        for (int c = 0; c < 4; ++c) {
            const bf16x8 b = *reinterpret_cast<const bf16x8*>(
                &fwT[(size_t)((((blockIdx.y * 35 + tt) << 2) + c) << 9) + lane * 8]);
            acc[c] = __builtin_amdgcn_mfma_f32_16x16x32_bf16(a, b, acc[c], 0, 0, 0);
        }
        __syncthreads();
    }
#pragma unroll
    for (int c = 0; c < 4; ++c) {
        const float bb = fb[c0 + c * 16 + m];
#pragma unroll
        for (int r = 0; r < 4; ++r) {
            const int rr = r0 + wave * 16 + q * 4 + r;
            if (rr < BGRAPH) out[(size_t)rr * 512 + c0 + c * 16 + m] = acc[c][r] + bb;
        }
    }
}

extern "C" void kernel_launch(void* const* d_in, const int* in_sizes, int n_in,
                              void* d_out, int out_size, void* d_ws, size_t ws_size,
                              hipStream_t stream) {
    const int*   pred_pairs = (const int*)d_in[0];
    const float* x          = (const float*)d_in[1];
    const int*   ei         = (const int*)d_in[2];
    const int*   bids       = (const int*)d_in[3];
    const float* ee         = (const float*)d_in[4];
    const float* w1_0 = (const float*)d_in[5];
    const float* b1_0 = (const float*)d_in[6];
    const float* w2_0 = (const float*)d_in[7];
    const float* b2_0 = (const float*)d_in[8];
    const float* w1_1 = (const float*)d_in[9];
    const float* b1_1 = (const float*)d_in[10];
    const float* w2_1 = (const float*)d_in[11];
    const float* b2_1 = (const float*)d_in[12];
    const float* w1_2 = (const float*)d_in[13];
    const float* b1_2 = (const float*)d_in[14];
    const float* w2_2 = (const float*)d_in[15];
    const float* b2_2 = (const float*)d_in[16];
    const float* lin_w   = (const float*)d_in[17];
    const float* lin_b   = (const float*)d_in[18];
    const float* final_w = (const float*)d_in[19];
    const float* final_b = (const float*)d_in[20];
    float* out = (float*)d_out;

    // workspace layout (16-B aligned regions)
    u16*   Y      = (u16*)d_ws;                          // 6,400,000 u16
    u16*   Hb     = Y + (size_t)N_NODES * 64;            // 6,400,000 u16
    int*   csr2   = (int*)(Hb + (size_t)N_NODES * 64);   // 4,800,000 int
    int*   deg    = csr2 + (size_t)N_NODES * CAP;        // 100,000 int
    float* pooled = (float*)(deg + N_NODES);             // 256,000 f
    float* counts = pooled + (size_t)BGRAPH * 64;        // 4,000 f
    u16*   A      = (u16*)(counts + BGRAPH);             // 4,448,000 u16
    u16*   w0T    = A + (size_t)BGRAPH * AIN;            // 28,672 u16 (frag-packed)
    u16*   fwT    = w0T + 64 * 448;                      // 573,440 u16 (frag-packed)
    u16*   wT5    = fwT + (size_t)512 * 1120;            // 5 x 4096 u16 (frag-packed)
    u16*   w2T0   = wT5;
    u16*   w1T1   = w2T0 + 4096;
    u16*   w2T1   = w1T1 + 4096;
    u16*   w1T2   = w2T1 + 4096;
    u16*   w2T2   = w1T2 + 4096;

    // zero deg + pooled + counts (adjacent)
    hipMemsetAsync(deg, 0, (size_t)(N_NODES + BGRAPH * 64 + BGRAPH) * sizeof(int), stream);

    k_prep_all<<<(PREP_TOT + 255) / 256, 256, 0, stream>>>(
        w1_0, final_w, w2_0, w1_1, w2_1, w1_2, w2_2, pred_pairs, ee,
        w0T, fwT, wT5, A);
    k_graph<<<(N_EDGES + 255) / 256, 256, 0, stream>>>(ei, deg, csr2, bids, counts);
    k_gemm_xw<<<(N_NODES + 63) / 64, 256, 0, stream>>>(x, w0T, Y);
    k_gin0<<<(N_NODES + 63) / 64, 256, 0, stream>>>(Y, deg, csr2, b1_0, w2T0, b2_0, Hb);
    k_gin<<<(N_NODES + 63) / 64, 256, 0, stream>>>(Hb, deg, csr2, w1T1, b1_1, w2T1, b2_1, Y);
    k_gin_pool<<<(N_NODES + 63) / 64, 256, 0, stream>>>(Y, deg, csr2, w1T2, b1_2, w2T2, b2_2, bids, pooled);
    k_emb<<<BGRAPH / 8, 256, 0, stream>>>(pooled, counts, lin_w, lin_b, A);
    k_final<<<dim3((BGRAPH + 63) / 64, 8), 256, 0, stream>>>(A, fwT, final_b, out);
}

// Round 10
// 547.391 us; speedup vs baseline: 1.1189x; 1.0151x over previous
//
#include <hip/hip_runtime.h>
#include <hip/hip_bf16.h>

#define N_NODES 100000
#define N_EDGES 800000
#define BGRAPH  4000
#define GNN_IN  428
#define HDIM    64
#define HID     512
#define EMBD    300
#define AIN     1112   // 512 + 600
#define CAP     48     // max in-degree capacity (Poisson(8); actual max ~30)
#define LSTR    72     // LDS row stride (ushorts): 2-way bank alias only (free, m136)
#define CSTR    136    // k_gemm_xw chunk LDS row stride (u16), 128 cols + 8 pad

typedef unsigned short u16;
typedef short bf16x8 __attribute__((ext_vector_type(8)));   // MFMA A/B frag (8 bf16, 4 VGPRs)
typedef float f32x4  __attribute__((ext_vector_type(4)));   // MFMA C/D frag

__device__ __forceinline__ u16 f2bf(float f) {
    union { float f; unsigned int u; } v; v.f = f;
    unsigned int r = v.u + 0x7FFFu + ((v.u >> 16) & 1u);    // RNE
    return (u16)(r >> 16);
}
__device__ __forceinline__ float bf2f(u16 u) {
    union { unsigned int u; float f; } v; v.u = ((unsigned int)u) << 16;
    return v.f;
}

// ---------------- merged prep (FRAGMENT-PACKED weights) ----------------
// Weights stored in MFMA-fragment order: every wave B-load is lane-contiguous
// (1 KB coalesced) instead of 16-row scattered (r6: 612 -> 560 us).
// Fragment f: 512 u16; (lane, j) at f*512 + lane*8 + j holds W[k][n],
// q=lane>>4, m=lane&15, k=k0(f)+q*8+j, n=n0(f)+m.
#define R_W0T   (64 * 448)          // 28672  = 56 frags (tt*4+c)
#define R_FWT   (512 * 1120)        // 573440 = 1120 frags ((c0b*35+tt)*4+c)
#define R_W64   (5 * 4096)          // 20480  = 5 x 8 frags (kk*4+c)
#define R_ORIG  (BGRAPH * 600)      // 2400000
#define PREP_TOT (R_W0T + R_FWT + R_W64 + R_ORIG)

__global__ void k_prep_all(const float* __restrict__ w1_0, const float* __restrict__ final_w,
                           const float* __restrict__ w2_0, const float* __restrict__ w1_1,
                           const float* __restrict__ w2_1, const float* __restrict__ w1_2,
                           const float* __restrict__ w2_2,
                           const int* __restrict__ pp, const float* __restrict__ ee,
                           u16* __restrict__ w0T, u16* __restrict__ fwT,
                           u16* __restrict__ wT5, u16* __restrict__ A) {
    int idx = blockIdx.x * 256 + threadIdx.x;
    if (idx < R_W0T) {  // w0 frag-pack: frag = tt*4+c
        const int frag = idx >> 9, lane = (idx >> 3) & 63, j = idx & 7;
        const int tt = frag >> 2, c = frag & 3;
        const int q = lane >> 4, m = lane & 15;
        const int k = tt * 32 + q * 8 + j, n = c * 16 + m;
        w0T[idx] = (k < GNN_IN) ? f2bf(w1_0[k * 64 + n]) : (u16)0;
        return;
    }
    idx -= R_W0T;
    if (idx < R_FWT) {  // final_w frag-pack: frag = (c0b*35+tt)*4+c
        const int frag = idx >> 9, lane = (idx >> 3) & 63, j = idx & 7;
        const int c0b = frag / 140, rem = frag - c0b * 140;
        const int tt = rem >> 2, c = rem & 3;
        const int q = lane >> 4, m = lane & 15;
        const int k = tt * 32 + q * 8 + j, n = c0b * 64 + c * 16 + m;
        fwT[idx] = (k < AIN) ? f2bf(final_w[(size_t)k * 512 + n]) : (u16)0;
        return;
    }
    idx -= R_FWT;
    if (idx < R_W64) {  // five 64x64 frag-packs: order w2_0, w1_1, w2_1, w1_2, w2_2
        const int which = idx >> 12;
        const int r = idx & 4095;
        const float* w = (which == 0) ? w2_0 : (which == 1) ? w1_1
                       : (which == 2) ? w2_1 : (which == 3) ? w1_2 : w2_2;
        const int frag = r >> 9, lane = (r >> 3) & 63, j = r & 7;
        const int kk = frag >> 2, c = frag & 3;
        const int q = lane >> 4, m = lane & 15;
        const int k = kk * 32 + q * 8 + j, n = c * 16 + m;
        wT5[(which << 12) + r] = f2bf(w[k * 64 + n]);
        return;
    }
    idx -= R_W64;
    if (idx < R_ORIG) { // A[:, 512:1112] = bf16(entity_embed[pred_pairs])
        const int b = idx / 600;
        const int j = idx - b * 600;
        const int which = (j >= 300) ? 1 : 0;
        const int cls = pp[b * 2 + which];
        A[(size_t)b * AIN + 512 + j] = f2bf(ee[cls * 300 + (j - which * 300)]);
    }
}

// ---------------- merged CSR fill + segment counts ----------------
__global__ void k_graph(const int* __restrict__ ei, int* __restrict__ deg,
                        int* __restrict__ csr2,
                        const int* __restrict__ bids, float* __restrict__ counts) {
    const int e = blockIdx.x * blockDim.x + threadIdx.x;
    if (e < N_EDGES) {
        const int s = ei[e];
        const int d = ei[N_EDGES + e];
        const int slot = atomicAdd(&deg[d], 1);
        if (slot < CAP) csr2[d * CAP + slot] = s;
    }
    if (e < N_NODES) {
        atomicAdd(&counts[bids[e]], 1.0f);
    }
}

// ---------------- y = bf16(x @ w1_0) — K-chunked LDS staging (17.4 KB) ----------
// r7 counters: 100us at 20% occupancy (58KB LDS -> 2 blocks/CU -> 1.6 waves/SIMD),
// all pipes idle => latency-bound from wave starvation. Chunking K into 128-col
// stages cuts LDS 58->17.4KB => ~8 blocks/CU, 4x wave supply, same coalescing.
__global__ __launch_bounds__(256) void k_gemm_xw(const float* __restrict__ x,
                                                 const u16* __restrict__ w0T,
                                                 u16* __restrict__ y) {
    __shared__ u16 xs[64 * CSTR];
    const int t = threadIdx.x;
    const int lane = t & 63, wave = t >> 6;
    const int q = lane >> 4, m = lane & 15;
    const int n0 = blockIdx.x * 64;

    f32x4 acc[4];
#pragma unroll
    for (int c = 0; c < 4; ++c) acc[c] = (f32x4){0.f, 0.f, 0.f, 0.f};

    // chunks 0..2: full 128 cols; chunk 3: cols 384..427 (11 float4) + zero pad
#pragma unroll 1
    for (int ch = 0; ch < 4; ++ch) {
        const int k0 = ch << 7;
        if (ch < 3) {
#pragma unroll
            for (int i = 0; i < 8; ++i) {
                const int idx4 = t + i * 256;            // 0..2047
                const int r = idx4 >> 5, c4 = idx4 & 31; // 64 rows x 32 float4
                const int gr = min(n0 + r, N_NODES - 1);
                const float4 v = *reinterpret_cast<const float4*>(
                    &x[(size_t)gr * GNN_IN + k0 + c4 * 4]);
                ushort4 o;
                o.x = f2bf(v.x); o.y = f2bf(v.y); o.z = f2bf(v.z); o.w = f2bf(v.w);
                *reinterpret_cast<ushort4*>(&xs[r * CSTR + c4 * 4]) = o;
            }
        } else {
#pragma unroll
            for (int i = 0; i < 8; ++i) {
                const int idx4 = t + i * 256;
                const int r = idx4 >> 5, c4 = idx4 & 31;
                const int gr = min(n0 + r, N_NODES - 1);
                ushort4 o = {0, 0, 0, 0};
                if (c4 < 11) {   // 428-384 = 44 cols = 11 float4 exactly
                    const float4 v = *reinterpret_cast<const float4*>(
                        &x[(size_t)gr * GNN_IN + k0 + c4 * 4]);
                    o.x = f2bf(v.x); o.y = f2bf(v.y); o.z = f2bf(v.z); o.w = f2bf(v.w);
                }
                *reinterpret_cast<ushort4*>(&xs[r * CSTR + c4 * 4]) = o;
            }
        }
        __syncthreads();
        const int nt = (ch < 3) ? 4 : 2;   // chunk 3 covers frags 12,13 only
        for (int tl = 0; tl < nt; ++tl) {
            const int ka = tl * 32 + q * 8;
            const bf16x8 a = *reinterpret_cast<const bf16x8*>(&xs[(wave * 16 + m) * CSTR + ka]);
            const int tt = (ch << 2) + tl;
#pragma unroll
            for (int c = 0; c < 4; ++c) {
                const bf16x8 b = *reinterpret_cast<const bf16x8*>(&w0T[(((tt << 2) + c) << 9) + lane * 8]);
                acc[c] = __builtin_amdgcn_mfma_f32_16x16x32_bf16(a, b, acc[c], 0, 0, 0);
            }
        }
        __syncthreads();
    }

    // C-layout: col = c*16 + m, row-in-tile = q*4 + r
#pragma unroll
    for (int c = 0; c < 4; ++c)
#pragma unroll
        for (int r = 0; r < 4; ++r) {
            const int rr = n0 + wave * 16 + q * 4 + r;
            if (rr < N_NODES) y[(size_t)rr * 64 + c * 16 + m] = f2bf(acc[c][r]);
        }
}

// wave-uniform chunk-8 gather: dg identical across the wave -> uniform branch.
__device__ __forceinline__ float gather8c(const u16* __restrict__ hin,
                                          const int* __restrict__ lst,
                                          int dg, int lane, float u) {
    const int4* l4 = reinterpret_cast<const int4*>(lst);
    for (int e = 0; e < dg; e += 8) {
        const int4 a = l4[e >> 2];
        const int4 b = l4[(e >> 2) + 1];
        int id[8] = {a.x, a.y, a.z, a.w, b.x, b.y, b.z, b.w};
        float v[8];
#pragma unroll
        for (int i = 0; i < 8; ++i) {
            const bool ok = (e + i < dg);
            const int idx = ok ? id[i] : 0;
            v[i] = bf2f(hin[(size_t)idx * 64 + lane]) * (ok ? 1.f : 0.f);
        }
#pragma unroll
        for (int i = 0; i < 8; ++i) u += v[i];
    }
    return u;
}

// ---------------- layer 0 (w1 pre-applied): h = relu(relu(u+b1) @ w2 + b2) ----------
// Barrier-free: LDS rows are wave-private. Weights frag-packed (coalesced loads).
__global__ __launch_bounds__(256, 4) void k_gin0(const u16* __restrict__ y,
                                                 const int* __restrict__ deg,
                                                 const int* __restrict__ csr2,
                                                 const float* __restrict__ b1,
                                                 const u16* __restrict__ w2T,
                                                 const float* __restrict__ b2,
                                                 u16* __restrict__ hout) {
    __shared__ u16 zs[64 * LSTR];
    const int t = threadIdx.x;
    const int lane = t & 63, wave = t >> 6;
    const int q = lane >> 4, m = lane & 15;
    const int n0 = blockIdx.x * 64;
    const int base = n0 + wave * 16;
    const float b1v = b1[lane];
#pragma unroll 4
    for (int j = 0; j < 16; ++j) {
        const int n = min(base + j, N_NODES - 1);
        const int dg = min(deg[n], CAP);
        float u = bf2f(y[(size_t)n * 64 + lane]);
        u = gather8c(y, &csr2[n * CAP], dg, lane, u);
        zs[(wave * 16 + j) * LSTR + lane] = f2bf(fmaxf(u + b1v, 0.f));
    }
    f32x4 acc[4];
#pragma unroll
    for (int c = 0; c < 4; ++c) acc[c] = (f32x4){0.f, 0.f, 0.f, 0.f};
    const bf16x8 a0 = *reinterpret_cast<const bf16x8*>(&zs[(wave * 16 + m) * LSTR + q * 8]);
    const bf16x8 a1 = *reinterpret_cast<const bf16x8*>(&zs[(wave * 16 + m) * LSTR + 32 + q * 8]);
#pragma unroll
    for (int c = 0; c < 4; ++c) {
        const bf16x8 bb0 = *reinterpret_cast<const bf16x8*>(&w2T[((0 + c) << 9) + lane * 8]);
        const bf16x8 bb1 = *reinterpret_cast<const bf16x8*>(&w2T[((4 + c) << 9) + lane * 8]);
        acc[c] = __builtin_amdgcn_mfma_f32_16x16x32_bf16(a0, bb0, acc[c], 0, 0, 0);
        acc[c] = __builtin_amdgcn_mfma_f32_16x16x32_bf16(a1, bb1, acc[c], 0, 0, 0);
    }
#pragma unroll
    for (int c = 0; c < 4; ++c) {
        const float bb = b2[c * 16 + m];
#pragma unroll
        for (int r = 0; r < 4; ++r) {
            const int n = n0 + wave * 16 + q * 4 + r;
            if (n < N_NODES) hout[(size_t)n * 64 + c * 16 + m] = f2bf(fmaxf(acc[c][r] + bb, 0.f));
        }
    }
}

// shared body for full GIN layer (barrier-free; frag-packed weights)
__device__ __forceinline__ void gin_mfma2(const u16* __restrict__ hin,
                                          const int* __restrict__ deg,
                                          const int* __restrict__ csr2,
                                          const u16* __restrict__ w1T,
                                          const float* __restrict__ b1,
                                          const u16* __restrict__ w2T,
                                          u16* us, u16* zs,
                                          int n0, int t, f32x4 acc[4]) {
    const int lane = t & 63, wave = t >> 6;
    const int q = lane >> 4, m = lane & 15;
    const int base = n0 + wave * 16;
#pragma unroll 4
    for (int j = 0; j < 16; ++j) {
        const int n = min(base + j, N_NODES - 1);
        const int dg = min(deg[n], CAP);
        float u = bf2f(hin[(size_t)n * 64 + lane]);
        u = gather8c(hin, &csr2[n * CAP], dg, lane, u);
        us[(wave * 16 + j) * LSTR + lane] = f2bf(u);
    }
    f32x4 z[4];
#pragma unroll
    for (int c = 0; c < 4; ++c) z[c] = (f32x4){0.f, 0.f, 0.f, 0.f};
    {
        const bf16x8 a0 = *reinterpret_cast<const bf16x8*>(&us[(wave * 16 + m) * LSTR + q * 8]);
        const bf16x8 a1 = *reinterpret_cast<const bf16x8*>(&us[(wave * 16 + m) * LSTR + 32 + q * 8]);
#pragma unroll
        for (int c = 0; c < 4; ++c) {
            const bf16x8 bb0 = *reinterpret_cast<const bf16x8*>(&w1T[((0 + c) << 9) + lane * 8]);
            const bf16x8 bb1 = *reinterpret_cast<const bf16x8*>(&w1T[((4 + c) << 9) + lane * 8]);
            z[c] = __builtin_amdgcn_mfma_f32_16x16x32_bf16(a0, bb0, z[c], 0, 0, 0);
            z[c] = __builtin_amdgcn_mfma_f32_16x16x32_bf16(a1, bb1, z[c], 0, 0, 0);
        }
    }
    // z epilogue -> zs (own-wave rows only; no barrier needed)
#pragma unroll
    for (int c = 0; c < 4; ++c) {
        const float bb = b1[c * 16 + m];
#pragma unroll
        for (int r = 0; r < 4; ++r)
            zs[(wave * 16 + q * 4 + r) * LSTR + c * 16 + m] = f2bf(fmaxf(z[c][r] + bb, 0.f));
    }
#pragma unroll
    for (int c = 0; c < 4; ++c) acc[c] = (f32x4){0.f, 0.f, 0.f, 0.f};
    {
        const bf16x8 a0 = *reinterpret_cast<const bf16x8*>(&zs[(wave * 16 + m) * LSTR + q * 8]);
        const bf16x8 a1 = *reinterpret_cast<const bf16x8*>(&zs[(wave * 16 + m) * LSTR + 32 + q * 8]);
#pragma unroll
        for (int c = 0; c < 4; ++c) {
            const bf16x8 bb0 = *reinterpret_cast<const bf16x8*>(&w2T[((0 + c) << 9) + lane * 8]);
            const bf16x8 bb1 = *reinterpret_cast<const bf16x8*>(&w2T[((4 + c) << 9) + lane * 8]);
            acc[c] = __builtin_amdgcn_mfma_f32_16x16x32_bf16(a0, bb0, acc[c], 0, 0, 0);
            acc[c] = __builtin_amdgcn_mfma_f32_16x16x32_bf16(a1, bb1, acc[c], 0, 0, 0);
        }
    }
}

// ---------------- layer 1: h' -> global bf16 ----------------
__global__ __launch_bounds__(256, 4) void k_gin(const u16* __restrict__ hin,
                                                const int* __restrict__ deg,
                                                const int* __restrict__ csr2,
                                                const u16* __restrict__ w1T,
                                                const float* __restrict__ b1,
                                                const u16* __restrict__ w2T,
                                                const float* __restrict__ b2,
                                                u16* __restrict__ hout) {
    __shared__ u16 us[64 * LSTR];
    __shared__ u16 zs[64 * LSTR];
    const int t = threadIdx.x;
    const int lane = t & 63, wave = t >> 6;
    const int q = lane >> 4, m = lane & 15;
    const int n0 = blockIdx.x * 64;
    f32x4 acc[4];
    gin_mfma2(hin, deg, csr2, w1T, b1, w2T, us, zs, n0, t, acc);
#pragma unroll
    for (int c = 0; c < 4; ++c) {
        const float bb = b2[c * 16 + m];
#pragma unroll
        for (int r = 0; r < 4; ++r) {
            const int n = n0 + wave * 16 + q * 4 + r;
            if (n < N_NODES) hout[(size_t)n * 64 + c * 16 + m] = f2bf(fmaxf(acc[c][r] + bb, 0.f));
        }
    }
}

// ---------------- layer 2 fused with mean-pool numerator (sorted batch_ids) ------
__global__ __launch_bounds__(256, 4) void k_gin_pool(const u16* __restrict__ hin,
                                                     const int* __restrict__ deg,
                                                     const int* __restrict__ csr2,
                                                     const u16* __restrict__ w1T,
                                                     const float* __restrict__ b1,
                                                     const u16* __restrict__ w2T,
                                                     const float* __restrict__ b2,
                                                     const int* __restrict__ bids,
                                                     float* __restrict__ pooled) {
    __shared__ u16 us[64 * LSTR];
    __shared__ u16 zs[64 * LSTR];
    const int t = threadIdx.x;
    const int lane = t & 63, wave = t >> 6;
    const int q = lane >> 4, m = lane & 15;
    const int n0 = blockIdx.x * 64;
    f32x4 acc[4];
    gin_mfma2(hin, deg, csr2, w1T, b1, w2T, us, zs, n0, t, acc);
    // store h into us (own-wave rows), then run-length segmented atomics
#pragma unroll
    for (int c = 0; c < 4; ++c) {
        const float bb = b2[c * 16 + m];
#pragma unroll
        for (int r = 0; r < 4; ++r)
            us[(wave * 16 + q * 4 + r) * LSTR + c * 16 + m] = f2bf(fmaxf(acc[c][r] + bb, 0.f));
    }
    const int base = n0 + wave * 16;
    if (base < N_NODES) {
        float s = 0.f;
        int cur = bids[base];
        for (int j = 0; j < 16; ++j) {
            const int n = base + j;
            if (n >= N_NODES) break;   // wave-uniform
            const int b = bids[n];
            const float h = bf2f(us[(wave * 16 + j) * LSTR + lane]);
            if (b != cur) {
                atomicAdd(&pooled[cur * 64 + lane], s);
                cur = b; s = h;
            } else {
                s += h;
            }
        }
        atomicAdd(&pooled[cur * 64 + lane], s);
    }
}

// ---------------- A[:, 0:512] = bf16((pooled/cnt) @ lin_w + lin_b) ----------------
__global__ __launch_bounds__(256) void k_emb(const float* __restrict__ pooled,
                                             const float* __restrict__ counts,
                                             const float* __restrict__ lw,
                                             const float* __restrict__ lb,
                                             u16* __restrict__ A) {
    __shared__ float prow[8][64];
    const int b0 = blockIdx.x * 8;
    const int t = threadIdx.x;
    const int lane = t & 63, wave = t >> 6;
    for (int i = 0; i < 2; ++i) {
        const int r = i * 4 + wave;
        const int b = b0 + r;
        const float c = fmaxf(counts[b], 1.0f);
        prow[r][lane] = pooled[b * 64 + lane] / c;
    }
    __syncthreads();
    for (int o = t; o < 512; o += 256) {
        float acc[8];
#pragma unroll
        for (int r = 0; r < 8; ++r) acc[r] = lb[o];
        for (int k = 0; k < 64; ++k) {
            const float wv = lw[k * 512 + o];
#pragma unroll
            for (int r = 0; r < 8; ++r) acc[r] += prow[r][k] * wv;
        }
#pragma unroll
        for (int r = 0; r < 8; ++r) A[(size_t)(b0 + r) * AIN + o] = f2bf(acc[r]);
    }
}

// ---------------- out = A @ final_w + final_b — MFMA, frag-packed B ----
__global__ __launch_bounds__(256) void k_final(const u16* __restrict__ A,
                                               const u16* __restrict__ fwT,
                                               const float* __restrict__ fb,
                                               float* __restrict__ out) {
    __shared__ u16 as[64 * 40];
    const int t = threadIdx.x;
    const int lane = t & 63, wave = t >> 6;
    const int q = lane >> 4, m = lane & 15;
    const int r0 = blockIdx.x * 64, c0 = blockIdx.y * 64;

    f32x4 acc[4];
#pragma unroll
    for (int c = 0; c < 4; ++c) acc[c] = (f32x4){0.f, 0.f, 0.f, 0.f};

    const int row = t >> 2, seg = t & 3;
    for (int k0 = 0; k0 < 1120; k0 += 32) {
        const int tt = k0 >> 5;
        const int gr = r0 + row, gk = k0 + seg * 8;
        uint4 v = {0u, 0u, 0u, 0u};
        if (gr < BGRAPH && gk < AIN)
            v = *reinterpret_cast<const uint4*>(&A[(size_t)gr * AIN + gk]);
        *reinterpret_cast<uint4*>(&as[row * 40 + seg * 8]) = v;
        __syncthreads();
        const bf16x8 a = *reinterpret_cast<const bf16x8*>(&as[(wave * 16 + m) * 40 + q * 8]);
#pragma unroll
        for (int c = 0; c < 4; ++c) {
            const bf16x8 b = *reinterpret_cast<const bf16x8*>(
                &fwT[(size_t)((((blockIdx.y * 35 + tt) << 2) + c) << 9) + lane * 8]);
            acc[c] = __builtin_amdgcn_mfma_f32_16x16x32_bf16(a, b, acc[c], 0, 0, 0);
        }
        __syncthreads();
    }
#pragma unroll
    for (int c = 0; c < 4; ++c) {
        const float bb = fb[c0 + c * 16 + m];
#pragma unroll
        for (int r = 0; r < 4; ++r) {
            const int rr = r0 + wave * 16 + q * 4 + r;
            if (rr < BGRAPH) out[(size_t)rr * 512 + c0 + c * 16 + m] = acc[c][r] + bb;
        }
    }
}

extern "C" void kernel_launch(void* const* d_in, const int* in_sizes, int n_in,
                              void* d_out, int out_size, void* d_ws, size_t ws_size,
                              hipStream_t stream) {
    const int*   pred_pairs = (const int*)d_in[0];
    const float* x          = (const float*)d_in[1];
    const int*   ei         = (const int*)d_in[2];
    const int*   bids       = (const int*)d_in[3];
    const float* ee         = (const float*)d_in[4];
    const float* w1_0 = (const float*)d_in[5];
    const float* b1_0 = (const float*)d_in[6];
    const float* w2_0 = (const float*)d_in[7];
    const float* b2_0 = (const float*)d_in[8];
    const float* w1_1 = (const float*)d_in[9];
    const float* b1_1 = (const float*)d_in[10];
    const float* w2_1 = (const float*)d_in[11];
    const float* b2_1 = (const float*)d_in[12];
    const float* w1_2 = (const float*)d_in[13];
    const float* b1_2 = (const float*)d_in[14];
    const float* w2_2 = (const float*)d_in[15];
    const float* b2_2 = (const float*)d_in[16];
    const float* lin_w   = (const float*)d_in[17];
    const float* lin_b   = (const float*)d_in[18];
    const float* final_w = (const float*)d_in[19];
    const float* final_b = (const float*)d_in[20];
    float* out = (float*)d_out;

    // workspace layout (16-B aligned regions)
    u16*   Y      = (u16*)d_ws;                          // 6,400,000 u16
    u16*   Hb     = Y + (size_t)N_NODES * 64;            // 6,400,000 u16
    int*   csr2   = (int*)(Hb + (size_t)N_NODES * 64);   // 4,800,000 int
    int*   deg    = csr2 + (size_t)N_NODES * CAP;        // 100,000 int
    float* pooled = (float*)(deg + N_NODES);             // 256,000 f
    float* counts = pooled + (size_t)BGRAPH * 64;        // 4,000 f
    u16*   A      = (u16*)(counts + BGRAPH);             // 4,448,000 u16
    u16*   w0T    = A + (size_t)BGRAPH * AIN;            // 28,672 u16 (frag-packed)
    u16*   fwT    = w0T + 64 * 448;                      // 573,440 u16 (frag-packed)
    u16*   wT5    = fwT + (size_t)512 * 1120;            // 5 x 4096 u16 (frag-packed)
    u16*   w2T0   = wT5;
    u16*   w1T1   = w2T0 + 4096;
    u16*   w2T1   = w1T1 + 4096;
    u16*   w1T2   = w2T1 + 4096;
    u16*   w2T2   = w1T2 + 4096;

    // zero deg + pooled + counts (adjacent)
    hipMemsetAsync(deg, 0, (size_t)(N_NODES + BGRAPH * 64 + BGRAPH) * sizeof(int), stream);

    k_prep_all<<<(PREP_TOT + 255) / 256, 256, 0, stream>>>(
        w1_0, final_w, w2_0, w1_1, w2_1, w1_2, w2_2, pred_pairs, ee,
        w0T, fwT, wT5, A);
    k_graph<<<(N_EDGES + 255) / 256, 256, 0, stream>>>(ei, deg, csr2, bids, counts);
    k_gemm_xw<<<(N_NODES + 63) / 64, 256, 0, stream>>>(x, w0T, Y);
    k_gin0<<<(N_NODES + 63) / 64, 256, 0, stream>>>(Y, deg, csr2, b1_0, w2T0, b2_0, Hb);
    k_gin<<<(N_NODES + 63) / 64, 256, 0, stream>>>(Hb, deg, csr2, w1T1, b1_1, w2T1, b2_1, Y);
    k_gin_pool<<<(N_NODES + 63) / 64, 256, 0, stream>>>(Y, deg, csr2, w1T2, b1_2, w2T2, b2_2, bids, pooled);
    k_emb<<<BGRAPH / 8, 256, 0, stream>>>(pooled, counts, lin_w, lin_b, A);
    k_final<<<dim3((BGRAPH + 63) / 64, 8), 256, 0, stream>>>(A, fwT, final_b, out);
}

// Round 11
// 512.021 us; speedup vs baseline: 1.1962x; 1.0691x over previous
//
#include <hip/hip_runtime.h>
#include <hip/hip_bf16.h>

#define N_NODES 100000
#define N_EDGES 800000
#define BGRAPH  4000
#define GNN_IN  428
#define HDIM    64
#define HID     512
#define EMBD    300
#define AIN     1112   // 512 + 600
#define CAP     48     // max in-degree capacity (Poisson(8); actual max ~30)
#define LSTR    72     // LDS row stride (ushorts): 2-way bank alias only (free, m136)
#define CSTR    136    // k_gemm_xw chunk LDS row stride (u16), 128 cols + 8 pad

typedef unsigned short u16;
typedef short bf16x8 __attribute__((ext_vector_type(8)));   // MFMA A/B frag (8 bf16, 4 VGPRs)
typedef float f32x4  __attribute__((ext_vector_type(4)));   // MFMA C/D frag

__device__ __forceinline__ u16 f2bf(float f) {
    union { float f; unsigned int u; } v; v.f = f;
    unsigned int r = v.u + 0x7FFFu + ((v.u >> 16) & 1u);    // RNE
    return (u16)(r >> 16);
}
__device__ __forceinline__ float bf2f(u16 u) {
    union { unsigned int u; float f; } v; v.u = ((unsigned int)u) << 16;
    return v.f;
}

// ---------------- merged prep (FRAGMENT-PACKED weights) ----------------
// Weights stored in MFMA-fragment order: every wave B-load is lane-contiguous
// (1 KB coalesced) instead of 16-row scattered (r6: 612 -> 560 us).
// Fragment f: 512 u16; (lane, j) at f*512 + lane*8 + j holds W[k][n],
// q=lane>>4, m=lane&15, k=k0(f)+q*8+j, n=n0(f)+m.
#define R_W0T   (64 * 448)          // 28672  = 56 frags (tt*4+c)
#define R_FWT   (512 * 1120)        // 573440 = 1120 frags ((c0b*35+tt)*4+c)
#define R_W64   (5 * 4096)          // 20480  = 5 x 8 frags (kk*4+c)
#define R_ORIG  (BGRAPH * 600)      // 2400000
#define PREP_TOT (R_W0T + R_FWT + R_W64 + R_ORIG)

__global__ void k_prep_all(const float* __restrict__ w1_0, const float* __restrict__ final_w,
                           const float* __restrict__ w2_0, const float* __restrict__ w1_1,
                           const float* __restrict__ w2_1, const float* __restrict__ w1_2,
                           const float* __restrict__ w2_2,
                           const int* __restrict__ pp, const float* __restrict__ ee,
                           u16* __restrict__ w0T, u16* __restrict__ fwT,
                           u16* __restrict__ wT5, u16* __restrict__ A) {
    int idx = blockIdx.x * 256 + threadIdx.x;
    if (idx < R_W0T) {  // w0 frag-pack: frag = tt*4+c
        const int frag = idx >> 9, lane = (idx >> 3) & 63, j = idx & 7;
        const int tt = frag >> 2, c = frag & 3;
        const int q = lane >> 4, m = lane & 15;
        const int k = tt * 32 + q * 8 + j, n = c * 16 + m;
        w0T[idx] = (k < GNN_IN) ? f2bf(w1_0[k * 64 + n]) : (u16)0;
        return;
    }
    idx -= R_W0T;
    if (idx < R_FWT) {  // final_w frag-pack: frag = (c0b*35+tt)*4+c
        const int frag = idx >> 9, lane = (idx >> 3) & 63, j = idx & 7;
        const int c0b = frag / 140, rem = frag - c0b * 140;
        const int tt = rem >> 2, c = rem & 3;
        const int q = lane >> 4, m = lane & 15;
        const int k = tt * 32 + q * 8 + j, n = c0b * 64 + c * 16 + m;
        fwT[idx] = (k < AIN) ? f2bf(final_w[(size_t)k * 512 + n]) : (u16)0;
        return;
    }
    idx -= R_FWT;
    if (idx < R_W64) {  // five 64x64 frag-packs: order w2_0, w1_1, w2_1, w1_2, w2_2
        const int which = idx >> 12;
        const int r = idx & 4095;
        const float* w = (which == 0) ? w2_0 : (which == 1) ? w1_1
                       : (which == 2) ? w2_1 : (which == 3) ? w1_2 : w2_2;
        const int frag = r >> 9, lane = (r >> 3) & 63, j = r & 7;
        const int kk = frag >> 2, c = frag & 3;
        const int q = lane >> 4, m = lane & 15;
        const int k = kk * 32 + q * 8 + j, n = c * 16 + m;
        wT5[(which << 12) + r] = f2bf(w[k * 64 + n]);
        return;
    }
    idx -= R_W64;
    if (idx < R_ORIG) { // A[:, 512:1112] = bf16(entity_embed[pred_pairs])
        const int b = idx / 600;
        const int j = idx - b * 600;
        const int which = (j >= 300) ? 1 : 0;
        const int cls = pp[b * 2 + which];
        A[(size_t)b * AIN + 512 + j] = f2bf(ee[cls * 300 + (j - which * 300)]);
    }
}

// ---------------- merged CSR fill + segment counts ----------------
__global__ void k_graph(const int* __restrict__ ei, int* __restrict__ deg,
                        int* __restrict__ csr2,
                        const int* __restrict__ bids, float* __restrict__ counts) {
    const int e = blockIdx.x * blockDim.x + threadIdx.x;
    if (e < N_EDGES) {
        const int s = ei[e];
        const int d = ei[N_EDGES + e];
        const int slot = atomicAdd(&deg[d], 1);
        if (slot < CAP) csr2[d * CAP + slot] = s;
    }
    if (e < N_NODES) {
        atomicAdd(&counts[bids[e]], 1.0f);
    }
}

// ---------------- y = bf16(x @ w1_0) — K-chunked LDS staging (17.4 KB) ----------
__global__ __launch_bounds__(256) void k_gemm_xw(const float* __restrict__ x,
                                                 const u16* __restrict__ w0T,
                                                 u16* __restrict__ y) {
    __shared__ u16 xs[64 * CSTR];
    const int t = threadIdx.x;
    const int lane = t & 63, wave = t >> 6;
    const int q = lane >> 4, m = lane & 15;
    const int n0 = blockIdx.x * 64;

    f32x4 acc[4];
#pragma unroll
    for (int c = 0; c < 4; ++c) acc[c] = (f32x4){0.f, 0.f, 0.f, 0.f};

    // chunks 0..2: full 128 cols; chunk 3: cols 384..427 (11 float4) + zero pad
#pragma unroll 1
    for (int ch = 0; ch < 4; ++ch) {
        const int k0 = ch << 7;
        if (ch < 3) {
#pragma unroll
            for (int i = 0; i < 8; ++i) {
                const int idx4 = t + i * 256;            // 0..2047
                const int r = idx4 >> 5, c4 = idx4 & 31; // 64 rows x 32 float4
                const int gr = min(n0 + r, N_NODES - 1);
                const float4 v = *reinterpret_cast<const float4*>(
                    &x[(size_t)gr * GNN_IN + k0 + c4 * 4]);
                ushort4 o;
                o.x = f2bf(v.x); o.y = f2bf(v.y); o.z = f2bf(v.z); o.w = f2bf(v.w);
                *reinterpret_cast<ushort4*>(&xs[r * CSTR + c4 * 4]) = o;
            }
        } else {
#pragma unroll
            for (int i = 0; i < 8; ++i) {
                const int idx4 = t + i * 256;
                const int r = idx4 >> 5, c4 = idx4 & 31;
                const int gr = min(n0 + r, N_NODES - 1);
                ushort4 o = {0, 0, 0, 0};
                if (c4 < 11) {   // 428-384 = 44 cols = 11 float4 exactly
                    const float4 v = *reinterpret_cast<const float4*>(
                        &x[(size_t)gr * GNN_IN + k0 + c4 * 4]);
                    o.x = f2bf(v.x); o.y = f2bf(v.y); o.z = f2bf(v.z); o.w = f2bf(v.w);
                }
                *reinterpret_cast<ushort4*>(&xs[r * CSTR + c4 * 4]) = o;
            }
        }
        __syncthreads();
        const int nt = (ch < 3) ? 4 : 2;   // chunk 3 covers frags 12,13 only
        for (int tl = 0; tl < nt; ++tl) {
            const int ka = tl * 32 + q * 8;
            const bf16x8 a = *reinterpret_cast<const bf16x8*>(&xs[(wave * 16 + m) * CSTR + ka]);
            const int tt = (ch << 2) + tl;
#pragma unroll
            for (int c = 0; c < 4; ++c) {
                const bf16x8 b = *reinterpret_cast<const bf16x8*>(&w0T[(((tt << 2) + c) << 9) + lane * 8]);
                acc[c] = __builtin_amdgcn_mfma_f32_16x16x32_bf16(a, b, acc[c], 0, 0, 0);
            }
        }
        __syncthreads();
    }

    // C-layout: col = c*16 + m, row-in-tile = q*4 + r
#pragma unroll
    for (int c = 0; c < 4; ++c)
#pragma unroll
        for (int r = 0; r < 4; ++r) {
            const int rr = n0 + wave * 16 + q * 4 + r;
            if (rr < N_NODES) y[(size_t)rr * 64 + c * 16 + m] = f2bf(acc[c][r]);
        }
}

// ---------------- paired gather: 2 nodes per wave, 4 B/lane ----------------
// Lanes 0-31 -> node nA, lanes 32-63 -> node nB; lane covers cols c2, c2+1.
// One row-load instruction now fetches 256 B (two nodes' rows) instead of 128 B:
// halves gather load-queue occupancy at identical byte traffic (r7/r10 showed
// instruction COUNT and ILP alone were not the lever; payload/slot is the test).
// dg is uniform per half-wave; loop bound = max over wave via one shfl_xor.
__device__ __forceinline__ void gather_pair(const u16* __restrict__ hin,
                                            const int* __restrict__ csr2,
                                            const int* __restrict__ deg,
                                            int n, int c2, float& u0, float& u1) {
    const int dg = min(deg[n], CAP);
    const unsigned int sv = *reinterpret_cast<const unsigned int*>(&hin[(size_t)n * 64 + c2]);
    u0 = bf2f((u16)(sv & 0xffffu));
    u1 = bf2f((u16)(sv >> 16));
    const int dgu = max(dg, __shfl_xor(dg, 32));
    const int4* l4 = reinterpret_cast<const int4*>(&csr2[n * CAP]);
    for (int e = 0; e < dgu; e += 8) {
        const int4 a = l4[e >> 2];
        const int4 b = l4[(e >> 2) + 1];
        int id[8] = {a.x, a.y, a.z, a.w, b.x, b.y, b.z, b.w};
        float v0[8], v1[8];
#pragma unroll
        for (int i = 0; i < 8; ++i) {
            const bool ok = (e + i < dg);
            const int idx = ok ? id[i] : 0;
            const unsigned int rv = *reinterpret_cast<const unsigned int*>(
                &hin[(size_t)idx * 64 + c2]);
            const float s = ok ? 1.f : 0.f;
            v0[i] = bf2f((u16)(rv & 0xffffu)) * s;
            v1[i] = bf2f((u16)(rv >> 16)) * s;
        }
#pragma unroll
        for (int i = 0; i < 8; ++i) { u0 += v0[i]; u1 += v1[i]; }
    }
}

// ---------------- layer 0 (w1 pre-applied): h = relu(relu(u+b1) @ w2 + b2) ----------
// Barrier-free: LDS rows are wave-private. Weights frag-packed (coalesced loads).
__global__ __launch_bounds__(256, 4) void k_gin0(const u16* __restrict__ y,
                                                 const int* __restrict__ deg,
                                                 const int* __restrict__ csr2,
                                                 const float* __restrict__ b1,
                                                 const u16* __restrict__ w2T,
                                                 const float* __restrict__ b2,
                                                 u16* __restrict__ hout) {
    __shared__ u16 zs[64 * LSTR];
    const int t = threadIdx.x;
    const int lane = t & 63, wave = t >> 6;
    const int q = lane >> 4, m = lane & 15;
    const int half = lane >> 5;
    const int c2 = (lane & 31) * 2;
    const int n0 = blockIdx.x * 64;
    const int base = n0 + wave * 16;
    const float2 b1v = *reinterpret_cast<const float2*>(&b1[c2]);
#pragma unroll 2
    for (int j = 0; j < 16; j += 2) {
        const int n = min(base + j + half, N_NODES - 1);
        float u0, u1;
        gather_pair(y, csr2, deg, n, c2, u0, u1);
        const unsigned int pw = (unsigned int)f2bf(fmaxf(u0 + b1v.x, 0.f))
                              | ((unsigned int)f2bf(fmaxf(u1 + b1v.y, 0.f)) << 16);
        *reinterpret_cast<unsigned int*>(&zs[(wave * 16 + j + half) * LSTR + c2]) = pw;
    }
    f32x4 acc[4];
#pragma unroll
    for (int c = 0; c < 4; ++c) acc[c] = (f32x4){0.f, 0.f, 0.f, 0.f};
    const bf16x8 a0 = *reinterpret_cast<const bf16x8*>(&zs[(wave * 16 + m) * LSTR + q * 8]);
    const bf16x8 a1 = *reinterpret_cast<const bf16x8*>(&zs[(wave * 16 + m) * LSTR + 32 + q * 8]);
#pragma unroll
    for (int c = 0; c < 4; ++c) {
        const bf16x8 bb0 = *reinterpret_cast<const bf16x8*>(&w2T[((0 + c) << 9) + lane * 8]);
        const bf16x8 bb1 = *reinterpret_cast<const bf16x8*>(&w2T[((4 + c) << 9) + lane * 8]);
        acc[c] = __builtin_amdgcn_mfma_f32_16x16x32_bf16(a0, bb0, acc[c], 0, 0, 0);
        acc[c] = __builtin_amdgcn_mfma_f32_16x16x32_bf16(a1, bb1, acc[c], 0, 0, 0);
    }
#pragma unroll
    for (int c = 0; c < 4; ++c) {
        const float bb = b2[c * 16 + m];
#pragma unroll
        for (int r = 0; r < 4; ++r) {
            const int n = n0 + wave * 16 + q * 4 + r;
            if (n < N_NODES) hout[(size_t)n * 64 + c * 16 + m] = f2bf(fmaxf(acc[c][r] + bb, 0.f));
        }
    }
}

// shared body for full GIN layer (barrier-free; frag-packed weights)
__device__ __forceinline__ void gin_mfma2(const u16* __restrict__ hin,
                                          const int* __restrict__ deg,
                                          const int* __restrict__ csr2,
                                          const u16* __restrict__ w1T,
                                          const float* __restrict__ b1,
                                          const u16* __restrict__ w2T,
                                          u16* us, u16* zs,
                                          int n0, int t, f32x4 acc[4]) {
    const int lane = t & 63, wave = t >> 6;
    const int q = lane >> 4, m = lane & 15;
    const int half = lane >> 5;
    const int c2 = (lane & 31) * 2;
    const int base = n0 + wave * 16;
#pragma unroll 2
    for (int j = 0; j < 16; j += 2) {
        const int n = min(base + j + half, N_NODES - 1);
        float u0, u1;
        gather_pair(hin, csr2, deg, n, c2, u0, u1);
        const unsigned int pw = (unsigned int)f2bf(u0) | ((unsigned int)f2bf(u1) << 16);
        *reinterpret_cast<unsigned int*>(&us[(wave * 16 + j + half) * LSTR + c2]) = pw;
    }
    f32x4 z[4];
#pragma unroll
    for (int c = 0; c < 4; ++c) z[c] = (f32x4){0.f, 0.f, 0.f, 0.f};
    {
        const bf16x8 a0 = *reinterpret_cast<const bf16x8*>(&us[(wave * 16 + m) * LSTR + q * 8]);
        const bf16x8 a1 = *reinterpret_cast<const bf16x8*>(&us[(wave * 16 + m) * LSTR + 32 + q * 8]);
#pragma unroll
        for (int c = 0; c < 4; ++c) {
            const bf16x8 bb0 = *reinterpret_cast<const bf16x8*>(&w1T[((0 + c) << 9) + lane * 8]);
            const bf16x8 bb1 = *reinterpret_cast<const bf16x8*>(&w1T[((4 + c) << 9) + lane * 8]);
            z[c] = __builtin_amdgcn_mfma_f32_16x16x32_bf16(a0, bb0, z[c], 0, 0, 0);
            z[c] = __builtin_amdgcn_mfma_f32_16x16x32_bf16(a1, bb1, z[c], 0, 0, 0);
        }
    }
    // z epilogue -> zs (own-wave rows only; no barrier needed)
#pragma unroll
    for (int c = 0; c < 4; ++c) {
        const float bb = b1[c * 16 + m];
#pragma unroll
        for (int r = 0; r < 4; ++r)
            zs[(wave * 16 + q * 4 + r) * LSTR + c * 16 + m] = f2bf(fmaxf(z[c][r] + bb, 0.f));
    }
#pragma unroll
    for (int c = 0; c < 4; ++c) acc[c] = (f32x4){0.f, 0.f, 0.f, 0.f};
    {
        const bf16x8 a0 = *reinterpret_cast<const bf16x8*>(&zs[(wave * 16 + m) * LSTR + q * 8]);
        const bf16x8 a1 = *reinterpret_cast<const bf16x8*>(&zs[(wave * 16 + m) * LSTR + 32 + q * 8]);
#pragma unroll
        for (int c = 0; c < 4; ++c) {
            const bf16x8 bb0 = *reinterpret_cast<const bf16x8*>(&w2T[((0 + c) << 9) + lane * 8]);
            const bf16x8 bb1 = *reinterpret_cast<const bf16x8*>(&w2T[((4 + c) << 9) + lane * 8]);
            acc[c] = __builtin_amdgcn_mfma_f32_16x16x32_bf16(a0, bb0, acc[c], 0, 0, 0);
            acc[c] = __builtin_amdgcn_mfma_f32_16x16x32_bf16(a1, bb1, acc[c], 0, 0, 0);
        }
    }
}

// ---------------- layer 1: h' -> global bf16 ----------------
__global__ __launch_bounds__(256, 4) void k_gin(const u16* __restrict__ hin,
                                                const int* __restrict__ deg,
                                                const int* __restrict__ csr2,
                                                const u16* __restrict__ w1T,
                                                const float* __restrict__ b1,
                                                const u16* __restrict__ w2T,
                                                const float* __restrict__ b2,
                                                u16* __restrict__ hout) {
    __shared__ u16 us[64 * LSTR];
    __shared__ u16 zs[64 * LSTR];
    const int t = threadIdx.x;
    const int lane = t & 63, wave = t >> 6;
    const int q = lane >> 4, m = lane & 15;
    const int n0 = blockIdx.x * 64;
    f32x4 acc[4];
    gin_mfma2(hin, deg, csr2, w1T, b1, w2T, us, zs, n0, t, acc);
#pragma unroll
    for (int c = 0; c < 4; ++c) {
        const float bb = b2[c * 16 + m];
#pragma unroll
        for (int r = 0; r < 4; ++r) {
            const int n = n0 + wave * 16 + q * 4 + r;
            if (n < N_NODES) hout[(size_t)n * 64 + c * 16 + m] = f2bf(fmaxf(acc[c][r] + bb, 0.f));
        }
    }
}

// ---------------- layer 2 fused with mean-pool numerator (sorted batch_ids) ------
__global__ __launch_bounds__(256, 4) void k_gin_pool(const u16* __restrict__ hin,
                                                     const int* __restrict__ deg,
                                                     const int* __restrict__ csr2,
                                                     const u16* __restrict__ w1T,
                                                     const float* __restrict__ b1,
                                                     const u16* __restrict__ w2T,
                                                     const float* __restrict__ b2,
                                                     const int* __restrict__ bids,
                                                     float* __restrict__ pooled) {
    __shared__ u16 us[64 * LSTR];
    __shared__ u16 zs[64 * LSTR];
    const int t = threadIdx.x;
    const int lane = t & 63, wave = t >> 6;
    const int q = lane >> 4, m = lane & 15;
    const int n0 = blockIdx.x * 64;
    f32x4 acc[4];
    gin_mfma2(hin, deg, csr2, w1T, b1, w2T, us, zs, n0, t, acc);
    // store h into us (own-wave rows), then run-length segmented atomics
#pragma unroll
    for (int c = 0; c < 4; ++c) {
        const float bb = b2[c * 16 + m];
#pragma unroll
        for (int r = 0; r < 4; ++r)
            us[(wave * 16 + q * 4 + r) * LSTR + c * 16 + m] = f2bf(fmaxf(acc[c][r] + bb, 0.f));
    }
    const int base = n0 + wave * 16;
    if (base < N_NODES) {
        float s = 0.f;
        int cur = bids[base];
        for (int j = 0; j < 16; ++j) {
            const int n = base + j;
            if (n >= N_NODES) break;   // wave-uniform
            const int b = bids[n];
            const float h = bf2f(us[(wave * 16 + j) * LSTR + lane]);
            if (b != cur) {
                atomicAdd(&pooled[cur * 64 + lane], s);
                cur = b; s = h;
            } else {
                s += h;
            }
        }
        atomicAdd(&pooled[cur * 64 + lane], s);
    }
}

// ---------------- A[:, 0:512] = bf16((pooled/cnt) @ lin_w + lin_b) ----------------
__global__ __launch_bounds__(256) void k_emb(const float* __restrict__ pooled,
                                             const float* __restrict__ counts,
                                             const float* __restrict__ lw,
                                             const float* __restrict__ lb,
                                             u16* __restrict__ A) {
    __shared__ float prow[8][64];
    const int b0 = blockIdx.x * 8;
    const int t = threadIdx.x;
    const int lane = t & 63, wave = t >> 6;
    for (int i = 0; i < 2; ++i) {
        const int r = i * 4 + wave;
        const int b = b0 + r;
        const float c = fmaxf(counts[b], 1.0f);
        prow[r][lane] = pooled[b * 64 + lane] / c;
    }
    __syncthreads();
    for (int o = t; o < 512; o += 256) {
        float acc[8];
#pragma unroll
        for (int r = 0; r < 8; ++r) acc[r] = lb[o];
        for (int k = 0; k < 64; ++k) {
            const float wv = lw[k * 512 + o];
#pragma unroll
            for (int r = 0; r < 8; ++r) acc[r] += prow[r][k] * wv;
        }
#pragma unroll
        for (int r = 0; r < 8; ++r) A[(size_t)(b0 + r) * AIN + o] = f2bf(acc[r]);
    }
}

// ---------------- out = A @ final_w + final_b — MFMA, frag-packed B ----
__global__ __launch_bounds__(256) void k_final(const u16* __restrict__ A,
                                               const u16* __restrict__ fwT,
                                               const float* __restrict__ fb,
                                               float* __restrict__ out) {
    __shared__ u16 as[64 * 40];
    const int t = threadIdx.x;
    const int lane = t & 63, wave = t >> 6;
    const int q = lane >> 4, m = lane & 15;
    const int r0 = blockIdx.x * 64, c0 = blockIdx.y * 64;

    f32x4 acc[4];
#pragma unroll
    for (int c = 0; c < 4; ++c) acc[c] = (f32x4){0.f, 0.f, 0.f, 0.f};

    const int row = t >> 2, seg = t & 3;
    for (int k0 = 0; k0 < 1120; k0 += 32) {
        const int tt = k0 >> 5;
        const int gr = r0 + row, gk = k0 + seg * 8;
        uint4 v = {0u, 0u, 0u, 0u};
        if (gr < BGRAPH && gk < AIN)
            v = *reinterpret_cast<const uint4*>(&A[(size_t)gr * AIN + gk]);
        *reinterpret_cast<uint4*>(&as[row * 40 + seg * 8]) = v;
        __syncthreads();
        const bf16x8 a = *reinterpret_cast<const bf16x8*>(&as[(wave * 16 + m) * 40 + q * 8]);
#pragma unroll
        for (int c = 0; c < 4; ++c) {
            const bf16x8 b = *reinterpret_cast<const bf16x8*>(
                &fwT[(size_t)((((blockIdx.y * 35 + tt) << 2) + c) << 9) + lane * 8]);
            acc[c] = __builtin_amdgcn_mfma_f32_16x16x32_bf16(a, b, acc[c], 0, 0, 0);
        }
        __syncthreads();
    }
#pragma unroll
    for (int c = 0; c < 4; ++c) {
        const float bb = fb[c0 + c * 16 + m];
#pragma unroll
        for (int r = 0; r < 4; ++r) {
            const int rr = r0 + wave * 16 + q * 4 + r;
            if (rr < BGRAPH) out[(size_t)rr * 512 + c0 + c * 16 + m] = acc[c][r] + bb;
        }
    }
}

extern "C" void kernel_launch(void* const* d_in, const int* in_sizes, int n_in,
                              void* d_out, int out_size, void* d_ws, size_t ws_size,
                              hipStream_t stream) {
    const int*   pred_pairs = (const int*)d_in[0];
    const float* x          = (const float*)d_in[1];
    const int*   ei         = (const int*)d_in[2];
    const int*   bids       = (const int*)d_in[3];
    const float* ee         = (const float*)d_in[4];
    const float* w1_0 = (const float*)d_in[5];
    const float* b1_0 = (const float*)d_in[6];
    const float* w2_0 = (const float*)d_in[7];
    const float* b2_0 = (const float*)d_in[8];
    const float* w1_1 = (const float*)d_in[9];
    const float* b1_1 = (const float*)d_in[10];
    const float* w2_1 = (const float*)d_in[11];
    const float* b2_1 = (const float*)d_in[12];
    const float* w1_2 = (const float*)d_in[13];
    const float* b1_2 = (const float*)d_in[14];
    const float* w2_2 = (const float*)d_in[15];
    const float* b2_2 = (const float*)d_in[16];
    const float* lin_w   = (const float*)d_in[17];
    const float* lin_b   = (const float*)d_in[18];
    const float* final_w = (const float*)d_in[19];
    const float* final_b = (const float*)d_in[20];
    float* out = (float*)d_out;

    // workspace layout (16-B aligned regions)
    u16*   Y      = (u16*)d_ws;                          // 6,400,000 u16
    u16*   Hb     = Y + (size_t)N_NODES * 64;            // 6,400,000 u16
    int*   csr2   = (int*)(Hb + (size_t)N_NODES * 64);   // 4,800,000 int
    int*   deg    = csr2 + (size_t)N_NODES * CAP;        // 100,000 int
    float* pooled = (float*)(deg + N_NODES);             // 256,000 f
    float* counts = pooled + (size_t)BGRAPH * 64;        // 4,000 f
    u16*   A      = (u16*)(counts + BGRAPH);             // 4,448,000 u16
    u16*   w0T    = A + (size_t)BGRAPH * AIN;            // 28,672 u16 (frag-packed)
    u16*   fwT    = w0T + 64 * 448;                      // 573,440 u16 (frag-packed)
    u16*   wT5    = fwT + (size_t)512 * 1120;            // 5 x 4096 u16 (frag-packed)
    u16*   w2T0   = wT5;
    u16*   w1T1   = w2T0 + 4096;
    u16*   w2T1   = w1T1 + 4096;
    u16*   w1T2   = w2T1 + 4096;
    u16*   w2T2   = w1T2 + 4096;

    // zero deg + pooled + counts (adjacent)
    hipMemsetAsync(deg, 0, (size_t)(N_NODES + BGRAPH * 64 + BGRAPH) * sizeof(int), stream);

    k_prep_all<<<(PREP_TOT + 255) / 256, 256, 0, stream>>>(
        w1_0, final_w, w2_0, w1_1, w2_1, w1_2, w2_2, pred_pairs, ee,
        w0T, fwT, wT5, A);
    k_graph<<<(N_EDGES + 255) / 256, 256, 0, stream>>>(ei, deg, csr2, bids, counts);
    k_gemm_xw<<<(N_NODES + 63) / 64, 256, 0, stream>>>(x, w0T, Y);
    k_gin0<<<(N_NODES + 63) / 64, 256, 0, stream>>>(Y, deg, csr2, b1_0, w2T0, b2_0, Hb);
    k_gin<<<(N_NODES + 63) / 64, 256, 0, stream>>>(Hb, deg, csr2, w1T1, b1_1, w2T1, b2_1, Y);
    k_gin_pool<<<(N_NODES + 63) / 64, 256, 0, stream>>>(Y, deg, csr2, w1T2, b1_2, w2T2, b2_2, bids, pooled);
    k_emb<<<BGRAPH / 8, 256, 0, stream>>>(pooled, counts, lin_w, lin_b, A);
    k_final<<<dim3((BGRAPH + 63) / 64, 8), 256, 0, stream>>>(A, fwT, final_b, out);
}